// Round 1
// baseline (455.007 us; speedup 1.0000x reference)
//
#include <hip/hip_runtime.h>
#include <math.h>
#include <cstddef>

#define BSZ 2
#define DM 256
#define LSEQ 4096
#define DIN 512
#define DXZ 1024
#define DS 16
#define RANK 16
#define GXP 48
#define LC 64
#define NC 64   // LSEQ / LC

__device__ __forceinline__ float silu_f(float x){ return x / (1.f + __expf(-x)); }
__device__ __forceinline__ float softplus_f(float x){ return fmaxf(x, 0.f) + log1pf(__expf(-fabsf(x))); }

// ---------------- LayerNorm + transpose (B,C,L) -> (B,L,C) ----------------
__global__ __launch_bounds__(256) void k_ln(const float* __restrict__ x,
                                            const float* __restrict__ lnw,
                                            const float* __restrict__ lnb,
                                            float* __restrict__ xn){
    __shared__ float tile[DM * 33];
    __shared__ float rsum[8][32], rsq[8][32];
    __shared__ float mu_s[32], rs_s[32];
    int b  = blockIdx.x >> 7;          // L/32 = 128 tiles per b
    int l0 = (blockIdx.x & 127) << 5;
    int tid = threadIdx.x;
    const float* xb = x + (size_t)b * DM * LSEQ;
    // stage: coalesced reads along l
    int lls = tid & 31, chi = tid >> 5;
    for (int cc = 0; cc < 32; ++cc){
        int c = cc * 8 + chi;
        tile[c * 33 + lls] = xb[(size_t)c * LSEQ + l0 + lls];
    }
    __syncthreads();
    // partial reduce: part = tid>>5 (8 parts), l = tid&31
    int part = tid >> 5, l = tid & 31;
    float s = 0.f, sq = 0.f;
    for (int i = 0; i < 32; ++i){
        float v = tile[(part * 32 + i) * 33 + l];
        s += v; sq += v * v;
    }
    rsum[part][l] = s; rsq[part][l] = sq;
    __syncthreads();
    if (tid < 32){
        float ts = 0.f, tq = 0.f;
        for (int p = 0; p < 8; ++p){ ts += rsum[p][tid]; tq += rsq[p][tid]; }
        float mu  = ts * (1.f / DM);
        float var = tq * (1.f / DM) - mu * mu;
        mu_s[tid] = mu;
        rs_s[tid] = rsqrtf(var + 1e-5f);
    }
    __syncthreads();
    // write: lanes sweep c for coalescing
    int c0 = tid & 63, lh = tid >> 6;
    for (int i = 0; i < 8; ++i){
        int ll = lh + 4 * i;
        float mu = mu_s[ll], rs = rs_s[ll];
        float* orow = xn + (size_t)(b * LSEQ + l0 + ll) * DM;
        for (int j = 0; j < 4; ++j){
            int c = c0 + 64 * j;
            orow[c] = (tile[c * 33 + ll] - mu) * rs * lnw[c] + lnb[c];
        }
    }
}

// ---------------- generic tiled GEMM: C[M,N] = A[M,K] @ W[N,K]^T ----------------
// EPI bits: 1 = add bias, 2 = softplus, 4 = accumulate into existing C
template<int EPI>
__global__ __launch_bounds__(256) void k_gemm(const float* __restrict__ A, int lda,
                                              const float* __restrict__ Wt,
                                              const float* __restrict__ bias,
                                              float* __restrict__ C, int ldc,
                                              int M, int N, int K){
    __shared__ float As[16][68];
    __shared__ float Ws[16][68];
    int bm = blockIdx.x * 64, bn = blockIdx.y * 64;
    int tid = threadIdx.x;
    int a_m = tid >> 2, a_k = (tid & 3) * 4;
    int tx = tid & 15, ty = tid >> 4;
    float acc[4][4] = {};
    for (int k0 = 0; k0 < K; k0 += 16){
        float4 av = *(const float4*)(A + (size_t)(bm + a_m) * lda + k0 + a_k);
        As[a_k + 0][a_m] = av.x; As[a_k + 1][a_m] = av.y;
        As[a_k + 2][a_m] = av.z; As[a_k + 3][a_m] = av.w;
        float4 wv = make_float4(0.f, 0.f, 0.f, 0.f);
        if (bn + a_m < N)
            wv = *(const float4*)(Wt + (size_t)(bn + a_m) * K + k0 + a_k);
        Ws[a_k + 0][a_m] = wv.x; Ws[a_k + 1][a_m] = wv.y;
        Ws[a_k + 2][a_m] = wv.z; Ws[a_k + 3][a_m] = wv.w;
        __syncthreads();
#pragma unroll
        for (int k = 0; k < 16; ++k){
            float4 a4 = *(const float4*)&As[k][ty * 4];
            float4 b4 = *(const float4*)&Ws[k][tx * 4];
            acc[0][0] += a4.x * b4.x; acc[0][1] += a4.x * b4.y; acc[0][2] += a4.x * b4.z; acc[0][3] += a4.x * b4.w;
            acc[1][0] += a4.y * b4.x; acc[1][1] += a4.y * b4.y; acc[1][2] += a4.y * b4.z; acc[1][3] += a4.y * b4.w;
            acc[2][0] += a4.z * b4.x; acc[2][1] += a4.z * b4.y; acc[2][2] += a4.z * b4.z; acc[2][3] += a4.z * b4.w;
            acc[3][0] += a4.w * b4.x; acc[3][1] += a4.w * b4.y; acc[3][2] += a4.w * b4.z; acc[3][3] += a4.w * b4.w;
        }
        __syncthreads();
    }
    int n = bn + tx * 4;
    if (n < N){
        float bx = 0.f, by = 0.f, bz = 0.f, bw = 0.f;
        if (EPI & 1){ bx = bias[n]; by = bias[n + 1]; bz = bias[n + 2]; bw = bias[n + 3]; }
#pragma unroll
        for (int i = 0; i < 4; ++i){
            int m = bm + ty * 4 + i;
            float4 r = make_float4(acc[i][0] + bx, acc[i][1] + by, acc[i][2] + bz, acc[i][3] + bw);
            if (EPI & 2){
                r.x = softplus_f(r.x); r.y = softplus_f(r.y);
                r.z = softplus_f(r.z); r.w = softplus_f(r.w);
            }
            float* cp = C + (size_t)m * ldc + n;
            if (EPI & 4){
                float4 old = *(const float4*)cp;
                r.x += old.x; r.y += old.y; r.z += old.z; r.w += old.w;
            }
            *(float4*)cp = r;
        }
    }
}

// ---------------- causal depthwise conv k=4 + SiLU ----------------
__global__ __launch_bounds__(256) void k_conv(const float* __restrict__ xz,
                                              const float* __restrict__ cw,
                                              const float* __restrict__ cb,
                                              float* __restrict__ xc){
    int idx = blockIdx.x * 256 + threadIdx.x;   // B*L*DIN
    int d  = idx & (DIN - 1);
    int bl = idx >> 9;
    int l  = bl & (LSEQ - 1);
    const float* base = xz + (size_t)bl * DXZ + d;
    float w0 = cw[d * 4], w1 = cw[d * 4 + 1], w2 = cw[d * 4 + 2], w3 = cw[d * 4 + 3];
    float acc = cb[d] + w3 * base[0];
    if (l >= 1) acc += w2 * base[-(ptrdiff_t)DXZ];
    if (l >= 2) acc += w1 * base[-(ptrdiff_t)(2 * DXZ)];
    if (l >= 3) acc += w0 * base[-(ptrdiff_t)(3 * DXZ)];
    xc[(size_t)bl * DIN + d] = silu_f(acc);
}

// ---------------- scan pass 1: per-chunk carries ----------------
__global__ __launch_bounds__(512) void k_scan1(const float* __restrict__ delta,
                                               const float* __restrict__ xc,
                                               const float* __restrict__ xdbl,
                                               const float* __restrict__ A_log,
                                               float* __restrict__ Acar,
                                               float* __restrict__ Bcar){
    int b = blockIdx.x >> 6;
    int c = blockIdx.x & 63;
    int d = threadIdx.x;
    __shared__ float Bs[LC][DS];
    for (int i = threadIdx.x; i < LC * DS; i += 512){
        int t = i >> 4, n = i & 15;
        Bs[t][n] = xdbl[(size_t)(b * LSEQ + c * LC + t) * GXP + RANK + n];
    }
    __syncthreads();
    float Av[16], ap[16], ac[16];
#pragma unroll
    for (int n = 0; n < 16; ++n){
        Av[n] = -__expf(A_log[d * 16 + n]);
        ap[n] = 1.f; ac[n] = 0.f;
    }
    const float* dp = delta + (size_t)(b * LSEQ + c * LC) * DIN + d;
    const float* xp = xc    + (size_t)(b * LSEQ + c * LC) * DIN + d;
    for (int t = 0; t < LC; ++t){
        float de = dp[(size_t)t * DIN];
        float u  = de * xp[(size_t)t * DIN];
#pragma unroll
        for (int n = 0; n < 16; ++n){
            float da = __expf(de * Av[n]);
            ap[n] *= da;
            ac[n] = da * ac[n] + u * Bs[t][n];
        }
    }
    size_t o = ((size_t)((c * BSZ + b) * DIN + d)) * 16;
#pragma unroll
    for (int n = 0; n < 16; n += 4){
        *(float4*)(Acar + o + n) = make_float4(ap[n], ap[n+1], ap[n+2], ap[n+3]);
        *(float4*)(Bcar + o + n) = make_float4(ac[n], ac[n+1], ac[n+2], ac[n+3]);
    }
}

// ---------------- scan pass 2: prefix over chunks ----------------
__global__ __launch_bounds__(256) void k_scan2(const float* __restrict__ Acar,
                                               const float* __restrict__ Bcar,
                                               float* __restrict__ hinit){
    int idx = blockIdx.x * 256 + threadIdx.x;   // B*DIN*16 = 16384
    float h = 0.f;
    for (int c = 0; c < NC; ++c){
        size_t o = (size_t)c * (BSZ * DIN * 16) + idx;
        hinit[o] = h;
        h = Acar[o] * h + Bcar[o];
    }
}

// ---------------- scan pass 3: replay + fused (y + D*xc)*silu(z) ----------------
__global__ __launch_bounds__(512) void k_scan3(const float* __restrict__ delta,
                                               const float* __restrict__ xc,
                                               const float* __restrict__ xz,
                                               const float* __restrict__ xdbl,
                                               const float* __restrict__ A_log,
                                               const float* __restrict__ D_ssm,
                                               const float* __restrict__ hinit,
                                               float* __restrict__ y){
    int b = blockIdx.x >> 6;
    int c = blockIdx.x & 63;
    int d = threadIdx.x;
    __shared__ float Bs[LC][DS], Cs[LC][DS];
    for (int i = threadIdx.x; i < LC * DS; i += 512){
        int t = i >> 4, n = i & 15;
        size_t r = (size_t)(b * LSEQ + c * LC + t) * GXP;
        Bs[t][n] = xdbl[r + RANK + n];
        Cs[t][n] = xdbl[r + RANK + DS + n];
    }
    __syncthreads();
    float Av[16], h[16];
    size_t ho = (size_t)c * (BSZ * DIN * 16) + (size_t)(b * DIN + d) * 16;
#pragma unroll
    for (int n = 0; n < 16; ++n){
        Av[n] = -__expf(A_log[d * 16 + n]);
        h[n]  = hinit[ho + n];
    }
    float Dd = D_ssm[d];
    size_t rb = (size_t)(b * LSEQ + c * LC);
    for (int t = 0; t < LC; ++t){
        size_t row = rb + t;
        float de  = delta[row * DIN + d];
        float xcv = xc[row * DIN + d];
        float u = de * xcv;
        float yv = 0.f;
#pragma unroll
        for (int n = 0; n < 16; ++n){
            float da = __expf(de * Av[n]);
            h[n] = da * h[n] + u * Bs[t][n];
            yv += h[n] * Cs[t][n];
        }
        float zv = xz[row * DXZ + DIN + d];
        y[row * DIN + d] = (yv + Dd * xcv) * silu_f(zv);   // y aliases delta (safe: same elem, read-then-write)
    }
}

// ---------------- 3x depthwise "same" conv + SiLU, accumulate into x_ssm ----------------
__global__ __launch_bounds__(256) void k_msconv(const float* __restrict__ xn,
                                                const float* __restrict__ c1w, const float* __restrict__ c1b,
                                                const float* __restrict__ c2w, const float* __restrict__ c2b,
                                                const float* __restrict__ c3w, const float* __restrict__ c3b,
                                                float* __restrict__ xssm){
    int idx = blockIdx.x * 256 + threadIdx.x;   // B*L*DM
    int cch = idx & (DM - 1);
    int bl  = idx >> 8;
    int l   = bl & (LSEQ - 1);
    int bL  = bl - l;
    float a1 = c1b[cch], a2 = c2b[cch], a3 = c3b[cch];
#pragma unroll
    for (int j = -3; j <= 3; ++j){
        int ll = l + j;
        if ((unsigned)ll < LSEQ){
            float v = xn[(size_t)(bL + ll) * DM + cch];
            if (j >= -1 && j <= 1) a1 += c1w[cch * 3 + (j + 1)] * v;
            if (j >= -2 && j <= 2) a2 += c2w[cch * 5 + (j + 2)] * v;
            a3 += c3w[cch * 7 + (j + 3)] * v;
        }
    }
    xssm[idx] += silu_f(a1) + silu_f(a2) + silu_f(a3);
}

// ---------------- final transpose + residual ----------------
__global__ __launch_bounds__(256) void k_out(const float* __restrict__ outlc,
                                             const float* __restrict__ x,
                                             float* __restrict__ out){
    __shared__ float tile[32][33];
    int bid = blockIdx.x;
    int lt = bid & 127;
    int ct = (bid >> 7) & 7;
    int b  = bid >> 10;
    int l0 = lt * 32, c0 = ct * 32;
    int tx = threadIdx.x & 31, ty = threadIdx.x >> 5;
    for (int r = 0; r < 32; r += 8)
        tile[ty + r][tx] = outlc[(size_t)(b * LSEQ + l0 + ty + r) * DM + c0 + tx];
    __syncthreads();
    for (int r = 0; r < 32; r += 8){
        int cc = c0 + ty + r;
        size_t o = (size_t)(b * DM + cc) * LSEQ + l0 + tx;
        out[o] = tile[tx][ty + r] + x[o];
    }
}

extern "C" void kernel_launch(void* const* d_in, const int* in_sizes, int n_in,
                              void* d_out, int out_size, void* d_ws, size_t ws_size,
                              hipStream_t stream){
    const float* x      = (const float*)d_in[0];
    const float* ln_w   = (const float*)d_in[1];
    const float* ln_b   = (const float*)d_in[2];
    const float* W_in   = (const float*)d_in[3];
    const float* conv_w = (const float*)d_in[4];
    const float* conv_b = (const float*)d_in[5];
    const float* W_xproj= (const float*)d_in[6];
    const float* W_dt   = (const float*)d_in[7];
    const float* b_dt   = (const float*)d_in[8];
    const float* A_log  = (const float*)d_in[9];
    const float* D_ssm  = (const float*)d_in[10];
    const float* W_outp = (const float*)d_in[11];
    const float* c1_w   = (const float*)d_in[12];
    const float* c1_b   = (const float*)d_in[13];
    const float* c2_w   = (const float*)d_in[14];
    const float* c2_b   = (const float*)d_in[15];
    const float* c3_w   = (const float*)d_in[16];
    const float* c3_b   = (const float*)d_in[17];
    const float* W_out  = (const float*)d_in[18];
    const float* b_out  = (const float*)d_in[19];
    const float* W_skip = (const float*)d_in[20];
    const float* b_skip = (const float*)d_in[21];
    float* out = (float*)d_out;

    float* ws    = (float*)d_ws;
    float* xn    = ws;                    // 2,097,152
    float* xz    = xn    + 2097152;       // 8,388,608
    float* xc    = xz    + 8388608;       // 4,194,304
    float* xdbl  = xc    + 4194304;       //   393,216
    float* delta = xdbl  + 393216;        // 4,194,304
    float* Acar  = delta + 4194304;       // 1,048,576
    float* Bcar  = Acar  + 1048576;       // 1,048,576
    float* hinit = Bcar  + 1048576;       // 1,048,576
    float* yb    = delta;                 // alias (delta dead after scan3)
    float* xssm  = xc;                    // alias (xc dead after scan3)
    float* outlc = xz;                    // alias (xz dead after scan3)

    const int M = BSZ * LSEQ;             // 8192

    k_ln<<<dim3(256), dim3(256), 0, stream>>>(x, ln_w, ln_b, xn);
    k_gemm<0><<<dim3(128, 16), dim3(256), 0, stream>>>(xn, DM, W_in, nullptr, xz, DXZ, M, DXZ, DM);
    k_conv<<<dim3(M * DIN / 256), dim3(256), 0, stream>>>(xz, conv_w, conv_b, xc);
    k_gemm<0><<<dim3(128, 1), dim3(256), 0, stream>>>(xc, DIN, W_xproj, nullptr, xdbl, GXP, M, GXP, DIN);
    k_gemm<3><<<dim3(128, 8), dim3(256), 0, stream>>>(xdbl, GXP, W_dt, b_dt, delta, DIN, M, DIN, RANK);
    k_scan1<<<dim3(BSZ * NC), dim3(512), 0, stream>>>(delta, xc, xdbl, A_log, Acar, Bcar);
    k_scan2<<<dim3(64), dim3(256), 0, stream>>>(Acar, Bcar, hinit);
    k_scan3<<<dim3(BSZ * NC), dim3(512), 0, stream>>>(delta, xc, xz, xdbl, A_log, D_ssm, hinit, yb);
    k_gemm<0><<<dim3(128, 4), dim3(256), 0, stream>>>(yb, DIN, W_outp, nullptr, xssm, DM, M, DM, DIN);
    k_msconv<<<dim3(M * DM / 256), dim3(256), 0, stream>>>(xn, c1_w, c1_b, c2_w, c2_b, c3_w, c3_b, xssm);
    k_gemm<1><<<dim3(128, 4), dim3(256), 0, stream>>>(xssm, DM, W_out, b_out, outlc, DM, M, DM, DM);
    k_gemm<5><<<dim3(128, 4), dim3(256), 0, stream>>>(xn, DM, W_skip, b_skip, outlc, DM, M, DM, DM);
    k_out<<<dim3(2048), dim3(256), 0, stream>>>(outlc, x, out);
}

// Round 2
// 304.278 us; speedup vs baseline: 1.4954x; 1.4954x over previous
//
#include <hip/hip_runtime.h>
#include <hip/hip_bf16.h>
#include <math.h>
#include <cstddef>

#define BSZ 2
#define DM 256
#define LSEQ 4096
#define DIN 512
#define DXZ 1024
#define DS 16
#define RANK 16
#define GXP 48
#define LC 64
#define NC 64   // LSEQ / LC

typedef __attribute__((ext_vector_type(8))) short short8;
typedef __attribute__((ext_vector_type(4))) float f32x4;
struct bf4 { __hip_bfloat16 v[4]; };

__device__ __forceinline__ float silu_f(float x){ return x / (1.f + __expf(-x)); }
__device__ __forceinline__ float softplus_f(float x){ return fmaxf(x, 0.f) + log1pf(__expf(-fabsf(x))); }
__device__ __forceinline__ float b2f(__hip_bfloat16 v){ return __bfloat162float(v); }
__device__ __forceinline__ __hip_bfloat16 f2b(float v){ return __float2bfloat16(v); }

__device__ __forceinline__ void gl_lds16(const void* g, void* s){
    __builtin_amdgcn_global_load_lds((const __attribute__((address_space(1))) void*)g,
                                     (__attribute__((address_space(3))) void*)s, 16, 0, 0);
}

// ---------------- LayerNorm + transpose (B,C,L) -> (B,L,C) bf16, into Acomb cols 256..511 ----------------
__global__ __launch_bounds__(256) void k_ln(const float* __restrict__ x,
                                            const float* __restrict__ lnw,
                                            const float* __restrict__ lnb,
                                            __hip_bfloat16* __restrict__ xnb){   // stride 512, already offset +256
    __shared__ float tile[DM * 33];
    __shared__ float rsum[8][32], rsq[8][32];
    __shared__ float mu_s[32], rs_s[32];
    int b  = blockIdx.x >> 7;
    int l0 = (blockIdx.x & 127) << 5;
    int tid = threadIdx.x;
    const float* xb = x + (size_t)b * DM * LSEQ;
    int lls = tid & 31, chi = tid >> 5;
    for (int cc = 0; cc < 32; ++cc){
        int c = cc * 8 + chi;
        tile[c * 33 + lls] = xb[(size_t)c * LSEQ + l0 + lls];
    }
    __syncthreads();
    int part = tid >> 5, l = tid & 31;
    float s = 0.f, sq = 0.f;
    for (int i = 0; i < 32; ++i){
        float v = tile[(part * 32 + i) * 33 + l];
        s += v; sq += v * v;
    }
    rsum[part][l] = s; rsq[part][l] = sq;
    __syncthreads();
    if (tid < 32){
        float ts = 0.f, tq = 0.f;
        for (int p = 0; p < 8; ++p){ ts += rsum[p][tid]; tq += rsq[p][tid]; }
        float mu  = ts * (1.f / DM);
        float var = tq * (1.f / DM) - mu * mu;
        mu_s[tid] = mu;
        rs_s[tid] = rsqrtf(var + 1e-5f);
    }
    __syncthreads();
    int c0 = tid & 63, lh = tid >> 6;
    for (int i = 0; i < 8; ++i){
        int ll = lh + 4 * i;
        float mu = mu_s[ll], rs = rs_s[ll];
        __hip_bfloat16* orow = xnb + (size_t)(b * LSEQ + l0 + ll) * 512;
        for (int j = 0; j < 4; ++j){
            int c = c0 + 64 * j;
            orow[c] = f2b((tile[c * 33 + ll] - mu) * rs * lnw[c] + lnb[c]);
        }
    }
}

// ---------------- weight conversion f32 -> bf16 (+pad/fuse) ----------------
__global__ __launch_bounds__(256) void k_cvtw(const float* __restrict__ W_in, const float* __restrict__ W_xproj,
                                              const float* __restrict__ W_outp, const float* __restrict__ W_out,
                                              const float* __restrict__ W_skip, const float* __restrict__ b_out,
                                              const float* __restrict__ b_skip,
                                              __hip_bfloat16* __restrict__ Winb, __hip_bfloat16* __restrict__ Wxpb,
                                              __hip_bfloat16* __restrict__ Wopb, __hip_bfloat16* __restrict__ Wcb,
                                              float* __restrict__ bc){
    int i0 = blockIdx.x * 256 + threadIdx.x;
    const int T = 256 * 256;
    for (int j = i0; j < 1024 * 256; j += T) Winb[j] = f2b(W_in[j]);
    for (int j = i0; j < 64 * 512; j += T){
        int r = j >> 9;
        Wxpb[j] = f2b(r < GXP ? W_xproj[r * 512 + (j & 511)] : 0.f);
    }
    for (int j = i0; j < 256 * 512; j += T) Wopb[j] = f2b(W_outp[j]);
    for (int j = i0; j < 256 * 512; j += T){
        int n = j >> 9, k = j & 511;
        Wcb[j] = f2b(k < 256 ? W_out[n * 256 + k] : W_skip[n * 256 + (k - 256)]);
    }
    if (i0 < 256) bc[i0] = b_out[i0] + b_skip[i0];
}

// ---------------- bf16 MFMA GEMM: C[M][ldc] = A[M][lda-strided] @ W[N][K]^T ----------------
// tile 128x64, BK=64, 256 thr = 4 waves (2M x 2N), wave tile 64x32, 16x16x32 MFMA
// EPI: 1 = +bias, 8 = bf16 output
template<int EPI>
__global__ __launch_bounds__(256) void k_mgemm(const __hip_bfloat16* __restrict__ A, int lda,
                                               const __hip_bfloat16* __restrict__ W,
                                               const float* __restrict__ bias,
                                               void* __restrict__ Cv, int ldc,
                                               int N, int K){
    __shared__ __align__(16) __hip_bfloat16 As[128 * 64];
    __shared__ __align__(16) __hip_bfloat16 Ws[64 * 64];
    const int tid = threadIdx.x;
    const int wave = tid >> 6, lane = tid & 63;
    const int brow = blockIdx.x * 128, bcol = blockIdx.y * 64;
    const int wm = wave >> 1, wn = wave & 1;

    // staging lane geometry: each 1024B wave-load covers 8 rows x 64 cols (bf16)
    const int a_row = lane >> 3;          // 0..7 within segment
    const int a_chk = lane & 7;           // 16B chunk within row
    const int a_scol = ((a_chk ^ a_row) * 8);   // swizzled source column (elements)

    const int lrow = lane & 15;
    const int kc = lane >> 4;             // 0..3
    const int r7 = lrow & 7;

    f32x4 acc[4][2] = {};

    for (int k0 = 0; k0 < K; k0 += 64){
        // A tile: 16 segments of 8 rows, 4 per wave
#pragma unroll
        for (int j = 0; j < 4; ++j){
            int seg = wave * 4 + j;
            const __hip_bfloat16* src = A + (size_t)(brow + seg * 8 + a_row) * lda + k0 + a_scol;
            gl_lds16(src, &As[seg * 512]);
        }
        // W tile: 8 segments, 2 per wave
#pragma unroll
        for (int j = 0; j < 2; ++j){
            int seg = wave * 2 + j;
            const __hip_bfloat16* src = W + (size_t)(bcol + seg * 8 + a_row) * K + k0 + a_scol;
            gl_lds16(src, &Ws[seg * 512]);
        }
        __syncthreads();
#pragma unroll
        for (int kk = 0; kk < 2; ++kk){
            int kchunk = kk * 4 + kc;
            short8 af[4], bfr[2];
#pragma unroll
            for (int mi = 0; mi < 4; ++mi){
                int row = wm * 64 + mi * 16 + lrow;
                af[mi] = *(const short8*)&As[row * 64 + ((kchunk ^ r7) * 8)];
            }
#pragma unroll
            for (int ni = 0; ni < 2; ++ni){
                int row = wn * 32 + ni * 16 + lrow;
                bfr[ni] = *(const short8*)&Ws[row * 64 + ((kchunk ^ r7) * 8)];
            }
#pragma unroll
            for (int mi = 0; mi < 4; ++mi)
#pragma unroll
                for (int ni = 0; ni < 2; ++ni)
                    acc[mi][ni] = __builtin_amdgcn_mfma_f32_16x16x32_bf16(af[mi], bfr[ni], acc[mi][ni], 0, 0, 0);
        }
        __syncthreads();
    }

    // epilogue: D col = lane&15, row = (lane>>4)*4 + r
#pragma unroll
    for (int ni = 0; ni < 2; ++ni){
        int n = bcol + wn * 32 + ni * 16 + lrow;
        if (n >= N) continue;
        float bv = (EPI & 1) ? bias[n] : 0.f;
#pragma unroll
        for (int mi = 0; mi < 4; ++mi){
            int m0 = brow + wm * 64 + mi * 16 + kc * 4;
#pragma unroll
            for (int r = 0; r < 4; ++r){
                float v = acc[mi][ni][r] + bv;
                if (EPI & 8) ((__hip_bfloat16*)Cv)[(size_t)(m0 + r) * ldc + n] = f2b(v);
                else         ((float*)Cv)[(size_t)(m0 + r) * ldc + n] = v;
            }
        }
    }
}

// ---------------- f32 GEMM for delta (K=16): delta = softplus(xdbl[:, :16] @ W_dt^T + b_dt), bf16 out ----------------
__global__ __launch_bounds__(256) void k_dtgemm(const float* __restrict__ A, int lda,
                                                const float* __restrict__ Wt,
                                                const float* __restrict__ bias,
                                                __hip_bfloat16* __restrict__ C, int ldc){
    __shared__ float As[16][68];
    __shared__ float Ws[16][68];
    int bm = blockIdx.x * 64, bn = blockIdx.y * 64;
    int tid = threadIdx.x;
    int a_m = tid >> 2, a_k = (tid & 3) * 4;
    int tx = tid & 15, ty = tid >> 4;
    float acc[4][4] = {};
    {
        float4 av = *(const float4*)(A + (size_t)(bm + a_m) * lda + a_k);
        As[a_k + 0][a_m] = av.x; As[a_k + 1][a_m] = av.y;
        As[a_k + 2][a_m] = av.z; As[a_k + 3][a_m] = av.w;
        float4 wv = *(const float4*)(Wt + (size_t)(bn + a_m) * 16 + a_k);
        Ws[a_k + 0][a_m] = wv.x; Ws[a_k + 1][a_m] = wv.y;
        Ws[a_k + 2][a_m] = wv.z; Ws[a_k + 3][a_m] = wv.w;
        __syncthreads();
#pragma unroll
        for (int k = 0; k < 16; ++k){
            float4 a4 = *(const float4*)&As[k][ty * 4];
            float4 b4 = *(const float4*)&Ws[k][tx * 4];
            acc[0][0] += a4.x * b4.x; acc[0][1] += a4.x * b4.y; acc[0][2] += a4.x * b4.z; acc[0][3] += a4.x * b4.w;
            acc[1][0] += a4.y * b4.x; acc[1][1] += a4.y * b4.y; acc[1][2] += a4.y * b4.z; acc[1][3] += a4.y * b4.w;
            acc[2][0] += a4.z * b4.x; acc[2][1] += a4.z * b4.y; acc[2][2] += a4.z * b4.z; acc[2][3] += a4.z * b4.w;
            acc[3][0] += a4.w * b4.x; acc[3][1] += a4.w * b4.y; acc[3][2] += a4.w * b4.z; acc[3][3] += a4.w * b4.w;
        }
    }
    int n = bn + tx * 4;
    float4 bb = *(const float4*)(bias + n);
#pragma unroll
    for (int i = 0; i < 4; ++i){
        int m = bm + ty * 4 + i;
        __hip_bfloat16* cp = C + (size_t)m * ldc + n;
        cp[0] = f2b(softplus_f(acc[i][0] + bb.x));
        cp[1] = f2b(softplus_f(acc[i][1] + bb.y));
        cp[2] = f2b(softplus_f(acc[i][2] + bb.z));
        cp[3] = f2b(softplus_f(acc[i][3] + bb.w));
    }
}

// ---------------- causal depthwise conv k=4 + SiLU (bf16 in/out, 4-wide) ----------------
__global__ __launch_bounds__(256) void k_conv(const __hip_bfloat16* __restrict__ xz,
                                              const float* __restrict__ cw,
                                              const float* __restrict__ cb,
                                              __hip_bfloat16* __restrict__ xc){
    int idx = blockIdx.x * 256 + threadIdx.x;   // B*L*DIN/4
    int d4 = (idx & 127) * 4;
    int bl = idx >> 7;
    int l  = bl & (LSEQ - 1);
    const __hip_bfloat16* base = xz + (size_t)bl * DXZ + d4;
    float4 bias = *(const float4*)(cb + d4);
    float acc[4] = {bias.x, bias.y, bias.z, bias.w};
    float4 w0 = *(const float4*)(cw + (d4 + 0) * 4);
    float4 w1 = *(const float4*)(cw + (d4 + 1) * 4);
    float4 w2 = *(const float4*)(cw + (d4 + 2) * 4);
    float4 w3 = *(const float4*)(cw + (d4 + 3) * 4);
    const float* wj[4] = {(const float*)&w0, (const float*)&w1, (const float*)&w2, (const float*)&w3};
#pragma unroll
    for (int t = 0; t < 4; ++t){
        int ls = l - (3 - t);
        if (ls >= 0){
            bf4 v = *(const bf4*)(base - (size_t)(3 - t) * DXZ);
#pragma unroll
            for (int j = 0; j < 4; ++j) acc[j] += wj[j][t] * b2f(v.v[j]);
        }
    }
    bf4 o;
#pragma unroll
    for (int j = 0; j < 4; ++j) o.v[j] = f2b(silu_f(acc[j]));
    *(bf4*)(xc + (size_t)bl * DIN + d4) = o;
}

// ---------------- scan pass 1: per-chunk carries ----------------
__global__ __launch_bounds__(512) void k_scan1(const __hip_bfloat16* __restrict__ delta,
                                               const __hip_bfloat16* __restrict__ xc,
                                               const float* __restrict__ xdbl,
                                               const float* __restrict__ A_log,
                                               float* __restrict__ Acar,
                                               float* __restrict__ Bcar){
    int b = blockIdx.x >> 6;
    int c = blockIdx.x & 63;
    int d = threadIdx.x;
    __shared__ float Bs[LC][DS];
    for (int i = threadIdx.x; i < LC * DS; i += 512){
        int t = i >> 4, n = i & 15;
        Bs[t][n] = xdbl[(size_t)(b * LSEQ + c * LC + t) * GXP + RANK + n];
    }
    __syncthreads();
    float Av[16], ap[16], ac[16];
#pragma unroll
    for (int n = 0; n < 16; ++n){
        Av[n] = -__expf(A_log[d * 16 + n]);
        ap[n] = 1.f; ac[n] = 0.f;
    }
    const __hip_bfloat16* dp = delta + (size_t)(b * LSEQ + c * LC) * DIN + d;
    const __hip_bfloat16* xp = xc    + (size_t)(b * LSEQ + c * LC) * DIN + d;
    for (int t = 0; t < LC; ++t){
        float de = b2f(dp[(size_t)t * DIN]);
        float u  = de * b2f(xp[(size_t)t * DIN]);
#pragma unroll
        for (int n = 0; n < 16; ++n){
            float da = __expf(de * Av[n]);
            ap[n] *= da;
            ac[n] = da * ac[n] + u * Bs[t][n];
        }
    }
    size_t o = ((size_t)((c * BSZ + b) * DIN + d)) * 16;
#pragma unroll
    for (int n = 0; n < 16; n += 4){
        *(float4*)(Acar + o + n) = make_float4(ap[n], ap[n+1], ap[n+2], ap[n+3]);
        *(float4*)(Bcar + o + n) = make_float4(ac[n], ac[n+1], ac[n+2], ac[n+3]);
    }
}

// ---------------- scan pass 2: prefix over chunks ----------------
__global__ __launch_bounds__(256) void k_scan2(const float* __restrict__ Acar,
                                               const float* __restrict__ Bcar,
                                               float* __restrict__ hinit){
    int idx = blockIdx.x * 256 + threadIdx.x;   // B*DIN*16 = 16384
    float h = 0.f;
    for (int c = 0; c < NC; ++c){
        size_t o = (size_t)c * (BSZ * DIN * 16) + idx;
        hinit[o] = h;
        h = Acar[o] * h + Bcar[o];
    }
}

// ---------------- scan pass 3: replay + fused (y + D*xc)*silu(z), bf16 out ----------------
__global__ __launch_bounds__(512) void k_scan3(const __hip_bfloat16* __restrict__ delta,
                                               const __hip_bfloat16* __restrict__ xc,
                                               const __hip_bfloat16* __restrict__ xz,
                                               const float* __restrict__ xdbl,
                                               const float* __restrict__ A_log,
                                               const float* __restrict__ D_ssm,
                                               const float* __restrict__ hinit,
                                               __hip_bfloat16* __restrict__ y){
    int b = blockIdx.x >> 6;
    int c = blockIdx.x & 63;
    int d = threadIdx.x;
    __shared__ float Bs[LC][DS], Cs[LC][DS];
    for (int i = threadIdx.x; i < LC * DS; i += 512){
        int t = i >> 4, n = i & 15;
        size_t r = (size_t)(b * LSEQ + c * LC + t) * GXP;
        Bs[t][n] = xdbl[r + RANK + n];
        Cs[t][n] = xdbl[r + RANK + DS + n];
    }
    __syncthreads();
    float Av[16], h[16];
    size_t ho = (size_t)c * (BSZ * DIN * 16) + (size_t)(b * DIN + d) * 16;
#pragma unroll
    for (int n = 0; n < 16; ++n){
        Av[n] = -__expf(A_log[d * 16 + n]);
        h[n]  = hinit[ho + n];
    }
    float Dd = D_ssm[d];
    size_t rb = (size_t)(b * LSEQ + c * LC);
    for (int t = 0; t < LC; ++t){
        size_t row = rb + t;
        float de  = b2f(delta[row * DIN + d]);
        float xcv = b2f(xc[row * DIN + d]);
        float u = de * xcv;
        float yv = 0.f;
#pragma unroll
        for (int n = 0; n < 16; ++n){
            float da = __expf(de * Av[n]);
            h[n] = da * h[n] + u * Bs[t][n];
            yv += h[n] * Cs[t][n];
        }
        float zv = b2f(xz[row * DXZ + DIN + d]);
        y[row * DIN + d] = f2b((yv + Dd * xcv) * silu_f(zv));
    }
}

// ---------------- 3x depthwise "same" conv + SiLU + xssm, write Acomb cols 0..255 bf16 ----------------
__global__ __launch_bounds__(256) void k_msconv(const __hip_bfloat16* __restrict__ xnb,  // Acomb+256, stride 512
                                                const __hip_bfloat16* __restrict__ xssm, // stride 256
                                                const float* __restrict__ c1w, const float* __restrict__ c1b,
                                                const float* __restrict__ c2w, const float* __restrict__ c2b,
                                                const float* __restrict__ c3w, const float* __restrict__ c3b,
                                                __hip_bfloat16* __restrict__ Acomb){     // stride 512
    int idx = blockIdx.x * 256 + threadIdx.x;   // B*L*DM
    int cch = idx & (DM - 1);
    int bl  = idx >> 8;
    int l   = bl & (LSEQ - 1);
    int bL  = bl - l;
    float a1 = c1b[cch], a2 = c2b[cch], a3 = c3b[cch];
#pragma unroll
    for (int j = -3; j <= 3; ++j){
        int ll = l + j;
        if ((unsigned)ll < LSEQ){
            float v = b2f(xnb[(size_t)(bL + ll) * 512 + cch]);
            if (j >= -1 && j <= 1) a1 += c1w[cch * 3 + (j + 1)] * v;
            if (j >= -2 && j <= 2) a2 += c2w[cch * 5 + (j + 2)] * v;
            a3 += c3w[cch * 7 + (j + 3)] * v;
        }
    }
    float res = b2f(xssm[(size_t)bl * 256 + cch]) + silu_f(a1) + silu_f(a2) + silu_f(a3);
    Acomb[(size_t)bl * 512 + cch] = f2b(res);
}

// ---------------- final transpose + residual ----------------
__global__ __launch_bounds__(256) void k_out(const float* __restrict__ outlc,
                                             const float* __restrict__ x,
                                             float* __restrict__ out){
    __shared__ float tile[32][33];
    int bid = blockIdx.x;
    int lt = bid & 127;
    int ct = (bid >> 7) & 7;
    int b  = bid >> 10;
    int l0 = lt * 32, c0 = ct * 32;
    int tx = threadIdx.x & 31, ty = threadIdx.x >> 5;
    for (int r = 0; r < 32; r += 8)
        tile[ty + r][tx] = outlc[(size_t)(b * LSEQ + l0 + ty + r) * DM + c0 + tx];
    __syncthreads();
    for (int r = 0; r < 32; r += 8){
        int cc = c0 + ty + r;
        size_t o = (size_t)(b * DM + cc) * LSEQ + l0 + tx;
        out[o] = tile[tx][ty + r] + x[o];
    }
}

extern "C" void kernel_launch(void* const* d_in, const int* in_sizes, int n_in,
                              void* d_out, int out_size, void* d_ws, size_t ws_size,
                              hipStream_t stream){
    const float* x      = (const float*)d_in[0];
    const float* ln_w   = (const float*)d_in[1];
    const float* ln_b   = (const float*)d_in[2];
    const float* W_in   = (const float*)d_in[3];
    const float* conv_w = (const float*)d_in[4];
    const float* conv_b = (const float*)d_in[5];
    const float* W_xproj= (const float*)d_in[6];
    const float* W_dt   = (const float*)d_in[7];
    const float* b_dt   = (const float*)d_in[8];
    const float* A_log  = (const float*)d_in[9];
    const float* D_ssm  = (const float*)d_in[10];
    const float* W_outp = (const float*)d_in[11];
    const float* c1_w   = (const float*)d_in[12];
    const float* c1_b   = (const float*)d_in[13];
    const float* c2_w   = (const float*)d_in[14];
    const float* c2_b   = (const float*)d_in[15];
    const float* c3_w   = (const float*)d_in[16];
    const float* c3_b   = (const float*)d_in[17];
    const float* W_out  = (const float*)d_in[18];
    const float* b_out  = (const float*)d_in[19];
    const float* W_skip = (const float*)d_in[20];
    const float* b_skip = (const float*)d_in[21];
    float* out = (float*)d_out;

    char* base = (char*)d_ws;
    const size_t MB = 1024 * 1024;
    __hip_bfloat16* Acomb = (__hip_bfloat16*)(base);            // [8192][512]  8 MB  (cols 0-255 xssm+conv, 256-511 xn)
    __hip_bfloat16* xzb   = (__hip_bfloat16*)(base + 8*MB);     // [8192][1024] 16 MB
    __hip_bfloat16* xcb   = (__hip_bfloat16*)(base + 24*MB);    // [8192][512]  8 MB
    float*          xdbl  = (float*)        (base + 32*MB);     // [8192][48]   1.5 MB
    __hip_bfloat16* deltab= (__hip_bfloat16*)(base + 34*MB);    // [8192][512]  8 MB
    float*          Acar  = (float*)        (base + 42*MB);     // 4 MB
    float*          Bcar  = (float*)        (base + 46*MB);     // 4 MB
    float*          hinit = (float*)        (base + 50*MB);     // 4 MB
    __hip_bfloat16* ybf   = (__hip_bfloat16*)(base + 54*MB);    // [8192][512]  8 MB
    __hip_bfloat16* xssmb = (__hip_bfloat16*)(base + 62*MB);    // [8192][256]  4 MB
    float*          outlc = (float*)        (base + 66*MB);     // [8192][256]  8 MB
    __hip_bfloat16* Winb  = (__hip_bfloat16*)(base + 74*MB);    // [1024][256]  512 KB
    __hip_bfloat16* Wxpb  = (__hip_bfloat16*)(base + 75*MB);    // [64][512]    64 KB (rows 48-63 zero)
    __hip_bfloat16* Wopb  = (__hip_bfloat16*)(base + 76*MB);    // [256][512]   256 KB
    __hip_bfloat16* Wcb   = (__hip_bfloat16*)(base + 77*MB);    // [256][512]   256 KB
    float*          bc    = (float*)        (base + 78*MB);     // 1 KB
    __hip_bfloat16* xnb   = Acomb + 256;                        // stride 512

    const int M = BSZ * LSEQ;   // 8192

    k_cvtw<<<dim3(256), dim3(256), 0, stream>>>(W_in, W_xproj, W_outp, W_out, W_skip, b_out, b_skip,
                                                Winb, Wxpb, Wopb, Wcb, bc);
    k_ln<<<dim3(256), dim3(256), 0, stream>>>(x, ln_w, ln_b, xnb);
    // xz = xn @ W_in^T               M=8192 N=1024 K=256
    k_mgemm<8><<<dim3(64, 16), dim3(256), 0, stream>>>(xnb, 512, Winb, nullptr, xzb, DXZ, 1024, 256);
    k_conv<<<dim3(M * DIN / 4 / 256), dim3(256), 0, stream>>>(xzb, conv_w, conv_b, xcb);
    // xdbl = xc @ W_xproj^T          M=8192 N=48 K=512  (f32 out)
    k_mgemm<0><<<dim3(64, 1), dim3(256), 0, stream>>>(xcb, 512, Wxpb, nullptr, xdbl, GXP, GXP, 512);
    // delta = softplus(xdbl @ W_dt^T + b_dt)   (f32 compute, bf16 out)
    k_dtgemm<<<dim3(128, 8), dim3(256), 0, stream>>>(xdbl, GXP, W_dt, b_dt, deltab, DIN);
    k_scan1<<<dim3(BSZ * NC), dim3(512), 0, stream>>>(deltab, xcb, xdbl, A_log, Acar, Bcar);
    k_scan2<<<dim3(64), dim3(256), 0, stream>>>(Acar, Bcar, hinit);
    k_scan3<<<dim3(BSZ * NC), dim3(512), 0, stream>>>(deltab, xcb, xzb, xdbl, A_log, D_ssm, hinit, ybf);
    // xssm = y @ W_outp^T            M=8192 N=256 K=512 (bf16 out)
    k_mgemm<8><<<dim3(64, 4), dim3(256), 0, stream>>>(ybf, 512, Wopb, nullptr, xssmb, 256, 256, 512);
    k_msconv<<<dim3(M * DM / 256), dim3(256), 0, stream>>>(xnb, xssmb, c1_w, c1_b, c2_w, c2_b, c3_w, c3_b, Acomb);
    // outlc = [xssm|xn] @ [W_out|W_skip]^T + (b_out+b_skip)   M=8192 N=256 K=512 (f32 out)
    k_mgemm<1><<<dim3(64, 4), dim3(256), 0, stream>>>(Acomb, 512, Wcb, bc, outlc, DM, 256, 512);
    k_out<<<dim3(2048), dim3(256), 0, stream>>>(outlc, x, out);
}

// Round 4
// 259.538 us; speedup vs baseline: 1.7531x; 1.1724x over previous
//
#include <hip/hip_runtime.h>
#include <hip/hip_bf16.h>
#include <math.h>
#include <cstddef>

#define BSZ 2
#define DM 256
#define LSEQ 4096
#define DIN 512
#define DXZ 1024
#define DS 16
#define RANK 16
#define GXP 48
#define LC 32
#define NC 128   // LSEQ / LC

typedef __attribute__((ext_vector_type(8))) short short8;
typedef __attribute__((ext_vector_type(4))) float f32x4;
struct bf4 { __hip_bfloat16 v[4]; };

__device__ __forceinline__ float silu_f(float x){ return x / (1.f + __expf(-x)); }
__device__ __forceinline__ float softplus_f(float x){ return fmaxf(x, 0.f) + log1pf(__expf(-fabsf(x))); }
__device__ __forceinline__ float b2f(__hip_bfloat16 v){ return __bfloat162float(v); }
__device__ __forceinline__ __hip_bfloat16 f2b(float v){ return __float2bfloat16(v); }

__device__ __forceinline__ void gl_lds16(const void* g, void* s){
    __builtin_amdgcn_global_load_lds((const __attribute__((address_space(1))) void*)g,
                                     (__attribute__((address_space(3))) void*)s, 16, 0, 0);
}

// ---------------- LayerNorm + transpose (B,C,L) -> (B,L,C) bf16, into Acomb cols 256..511 ----------------
__global__ __launch_bounds__(256) void k_ln(const float* __restrict__ x,
                                            const float* __restrict__ lnw,
                                            const float* __restrict__ lnb,
                                            __hip_bfloat16* __restrict__ xnb){   // stride 512, already offset +256
    __shared__ float tile[DM * 33];
    __shared__ float rsum[8][32], rsq[8][32];
    __shared__ float mu_s[32], rs_s[32];
    int b  = blockIdx.x >> 7;
    int l0 = (blockIdx.x & 127) << 5;
    int tid = threadIdx.x;
    const float* xb = x + (size_t)b * DM * LSEQ;
    int lls = tid & 31, chi = tid >> 5;
    for (int cc = 0; cc < 32; ++cc){
        int c = cc * 8 + chi;
        tile[c * 33 + lls] = xb[(size_t)c * LSEQ + l0 + lls];
    }
    __syncthreads();
    int part = tid >> 5, l = tid & 31;
    float s = 0.f, sq = 0.f;
    for (int i = 0; i < 32; ++i){
        float v = tile[(part * 32 + i) * 33 + l];
        s += v; sq += v * v;
    }
    rsum[part][l] = s; rsq[part][l] = sq;
    __syncthreads();
    if (tid < 32){
        float ts = 0.f, tq = 0.f;
        for (int p = 0; p < 8; ++p){ ts += rsum[p][tid]; tq += rsq[p][tid]; }
        float mu  = ts * (1.f / DM);
        float var = tq * (1.f / DM) - mu * mu;
        mu_s[tid] = mu;
        rs_s[tid] = rsqrtf(var + 1e-5f);
    }
    __syncthreads();
    int c0 = tid & 63, lh = tid >> 6;
    for (int i = 0; i < 8; ++i){
        int ll = lh + 4 * i;
        float mu = mu_s[ll], rs = rs_s[ll];
        __hip_bfloat16* orow = xnb + (size_t)(b * LSEQ + l0 + ll) * 512;
        for (int j = 0; j < 4; ++j){
            int c = c0 + 64 * j;
            orow[c] = f2b((tile[c * 33 + ll] - mu) * rs * lnw[c] + lnb[c]);
        }
    }
}

// ---------------- weight conversion f32 -> bf16 (+pad/fuse) ----------------
__global__ __launch_bounds__(256) void k_cvtw(const float* __restrict__ W_in, const float* __restrict__ W_xproj,
                                              const float* __restrict__ W_outp, const float* __restrict__ W_out,
                                              const float* __restrict__ W_skip, const float* __restrict__ b_out,
                                              const float* __restrict__ b_skip,
                                              __hip_bfloat16* __restrict__ Winb, __hip_bfloat16* __restrict__ Wxpb,
                                              __hip_bfloat16* __restrict__ Wopb, __hip_bfloat16* __restrict__ Wcb,
                                              float* __restrict__ bc){
    int i0 = blockIdx.x * 256 + threadIdx.x;
    const int T = 256 * 256;
    for (int j = i0; j < 1024 * 256; j += T) Winb[j] = f2b(W_in[j]);
    for (int j = i0; j < 64 * 512; j += T){
        int r = j >> 9;
        Wxpb[j] = f2b(r < GXP ? W_xproj[r * 512 + (j & 511)] : 0.f);
    }
    for (int j = i0; j < 256 * 512; j += T) Wopb[j] = f2b(W_outp[j]);
    for (int j = i0; j < 256 * 512; j += T){
        int n = j >> 9, k = j & 511;
        Wcb[j] = f2b(k < 256 ? W_out[n * 256 + k] : W_skip[n * 256 + (k - 256)]);
    }
    if (i0 < 256) bc[i0] = b_out[i0] + b_skip[i0];
}

// ---------------- bf16 MFMA GEMM: C[M][ldc] = A[M][lda-strided] @ W[N][K]^T ----------------
// tile 128x64, BK=64, 256 thr = 4 waves (2M x 2N), wave tile 64x32, 16x16x32 MFMA
// EPI: 1 = +bias, 8 = bf16 output
template<int EPI>
__global__ __launch_bounds__(256) void k_mgemm(const __hip_bfloat16* __restrict__ A, int lda,
                                               const __hip_bfloat16* __restrict__ W,
                                               const float* __restrict__ bias,
                                               void* __restrict__ Cv, int ldc,
                                               int N, int K){
    __shared__ __align__(16) __hip_bfloat16 As[128 * 64];
    __shared__ __align__(16) __hip_bfloat16 Ws[64 * 64];
    const int tid = threadIdx.x;
    const int wave = tid >> 6, lane = tid & 63;
    const int brow = blockIdx.x * 128, bcol = blockIdx.y * 64;
    const int wm = wave >> 1, wn = wave & 1;

    const int a_row = lane >> 3;          // 0..7 within segment
    const int a_chk = lane & 7;           // 16B chunk within row
    const int a_scol = ((a_chk ^ a_row) * 8);   // swizzled source column (elements)

    const int lrow = lane & 15;
    const int kc = lane >> 4;             // 0..3
    const int r7 = lrow & 7;

    f32x4 acc[4][2] = {};

    for (int k0 = 0; k0 < K; k0 += 64){
#pragma unroll
        for (int j = 0; j < 4; ++j){
            int seg = wave * 4 + j;
            const __hip_bfloat16* src = A + (size_t)(brow + seg * 8 + a_row) * lda + k0 + a_scol;
            gl_lds16(src, &As[seg * 512]);
        }
#pragma unroll
        for (int j = 0; j < 2; ++j){
            int seg = wave * 2 + j;
            const __hip_bfloat16* src = W + (size_t)(bcol + seg * 8 + a_row) * K + k0 + a_scol;
            gl_lds16(src, &Ws[seg * 512]);
        }
        __syncthreads();
#pragma unroll
        for (int kk = 0; kk < 2; ++kk){
            int kchunk = kk * 4 + kc;
            short8 af[4], bfr[2];
#pragma unroll
            for (int mi = 0; mi < 4; ++mi){
                int row = wm * 64 + mi * 16 + lrow;
                af[mi] = *(const short8*)&As[row * 64 + ((kchunk ^ r7) * 8)];
            }
#pragma unroll
            for (int ni = 0; ni < 2; ++ni){
                int row = wn * 32 + ni * 16 + lrow;
                bfr[ni] = *(const short8*)&Ws[row * 64 + ((kchunk ^ r7) * 8)];
            }
#pragma unroll
            for (int mi = 0; mi < 4; ++mi)
#pragma unroll
                for (int ni = 0; ni < 2; ++ni)
                    acc[mi][ni] = __builtin_amdgcn_mfma_f32_16x16x32_bf16(af[mi], bfr[ni], acc[mi][ni], 0, 0, 0);
        }
        __syncthreads();
    }

#pragma unroll
    for (int ni = 0; ni < 2; ++ni){
        int n = bcol + wn * 32 + ni * 16 + lrow;
        if (n >= N) continue;
        float bv = (EPI & 1) ? bias[n] : 0.f;
#pragma unroll
        for (int mi = 0; mi < 4; ++mi){
            int m0 = brow + wm * 64 + mi * 16 + kc * 4;
#pragma unroll
            for (int r = 0; r < 4; ++r){
                float v = acc[mi][ni][r] + bv;
                if (EPI & 8) ((__hip_bfloat16*)Cv)[(size_t)(m0 + r) * ldc + n] = f2b(v);
                else         ((float*)Cv)[(size_t)(m0 + r) * ldc + n] = v;
            }
        }
    }
}

// ---------------- f32 GEMM for delta (K=16): delta = softplus(xdbl[:, :16] @ W_dt^T + b_dt), bf16 out ----------------
__global__ __launch_bounds__(256) void k_dtgemm(const float* __restrict__ A, int lda,
                                                const float* __restrict__ Wt,
                                                const float* __restrict__ bias,
                                                __hip_bfloat16* __restrict__ C, int ldc){
    __shared__ float As[16][68];
    __shared__ float Ws[16][68];
    int bm = blockIdx.x * 64, bn = blockIdx.y * 64;
    int tid = threadIdx.x;
    int a_m = tid >> 2, a_k = (tid & 3) * 4;
    int tx = tid & 15, ty = tid >> 4;
    float acc[4][4] = {};
    {
        float4 av = *(const float4*)(A + (size_t)(bm + a_m) * lda + a_k);
        As[a_k + 0][a_m] = av.x; As[a_k + 1][a_m] = av.y;
        As[a_k + 2][a_m] = av.z; As[a_k + 3][a_m] = av.w;
        float4 wv = *(const float4*)(Wt + (size_t)(bn + a_m) * 16 + a_k);
        Ws[a_k + 0][a_m] = wv.x; Ws[a_k + 1][a_m] = wv.y;
        Ws[a_k + 2][a_m] = wv.z; Ws[a_k + 3][a_m] = wv.w;
        __syncthreads();
#pragma unroll
        for (int k = 0; k < 16; ++k){
            float4 a4 = *(const float4*)&As[k][ty * 4];
            float4 b4 = *(const float4*)&Ws[k][tx * 4];
            acc[0][0] += a4.x * b4.x; acc[0][1] += a4.x * b4.y; acc[0][2] += a4.x * b4.z; acc[0][3] += a4.x * b4.w;
            acc[1][0] += a4.y * b4.x; acc[1][1] += a4.y * b4.y; acc[1][2] += a4.y * b4.z; acc[1][3] += a4.y * b4.w;
            acc[2][0] += a4.z * b4.x; acc[2][1] += a4.z * b4.y; acc[2][2] += a4.z * b4.z; acc[2][3] += a4.z * b4.w;
            acc[3][0] += a4.w * b4.x; acc[3][1] += a4.w * b4.y; acc[3][2] += a4.w * b4.z; acc[3][3] += a4.w * b4.w;
        }
    }
    int n = bn + tx * 4;
    float4 bb = *(const float4*)(bias + n);
#pragma unroll
    for (int i = 0; i < 4; ++i){
        int m = bm + ty * 4 + i;
        __hip_bfloat16* cp = C + (size_t)m * ldc + n;
        cp[0] = f2b(softplus_f(acc[i][0] + bb.x));
        cp[1] = f2b(softplus_f(acc[i][1] + bb.y));
        cp[2] = f2b(softplus_f(acc[i][2] + bb.z));
        cp[3] = f2b(softplus_f(acc[i][3] + bb.w));
    }
}

// ---------------- causal depthwise conv k=4 + SiLU (bf16 in/out, 4-wide) ----------------
__global__ __launch_bounds__(256) void k_conv(const __hip_bfloat16* __restrict__ xz,
                                              const float* __restrict__ cw,
                                              const float* __restrict__ cb,
                                              __hip_bfloat16* __restrict__ xc){
    int idx = blockIdx.x * 256 + threadIdx.x;   // B*L*DIN/4
    int d4 = (idx & 127) * 4;
    int bl = idx >> 7;
    int l  = bl & (LSEQ - 1);
    const __hip_bfloat16* base = xz + (size_t)bl * DXZ + d4;
    float4 bias = *(const float4*)(cb + d4);
    float acc[4] = {bias.x, bias.y, bias.z, bias.w};
    float4 w0 = *(const float4*)(cw + (d4 + 0) * 4);
    float4 w1 = *(const float4*)(cw + (d4 + 1) * 4);
    float4 w2 = *(const float4*)(cw + (d4 + 2) * 4);
    float4 w3 = *(const float4*)(cw + (d4 + 3) * 4);
    const float* wj[4] = {(const float*)&w0, (const float*)&w1, (const float*)&w2, (const float*)&w3};
#pragma unroll
    for (int t = 0; t < 4; ++t){
        int ls = l - (3 - t);
        if (ls >= 0){
            bf4 v = *(const bf4*)(base - (size_t)(3 - t) * DXZ);
#pragma unroll
            for (int j = 0; j < 4; ++j) acc[j] += wj[j][t] * b2f(v.v[j]);
        }
    }
    bf4 o;
#pragma unroll
    for (int j = 0; j < 4; ++j) o.v[j] = f2b(silu_f(acc[j]));
    *(bf4*)(xc + (size_t)bl * DIN + d4) = o;
}

// ---------------- scan pass 1: per-chunk carries, n-split x2 ----------------
// grid: [b(1b) | c(7b) | dh(1b)]; block 512: dloc = tid>>1, nh = tid&1
__global__ __launch_bounds__(512) void k_scan1(const __hip_bfloat16* __restrict__ delta,
                                               const __hip_bfloat16* __restrict__ xc,
                                               const float* __restrict__ xdbl,
                                               const float* __restrict__ A_log,
                                               float* __restrict__ Acar,
                                               float* __restrict__ Bcar){
    int bx = blockIdx.x;
    int dh = bx & 1;
    int c  = (bx >> 1) & (NC - 1);
    int b  = bx >> 8;
    int tid = threadIdx.x;
    int dloc = tid >> 1, nh = tid & 1;
    int d = dh * 256 + dloc;
    int n0 = nh * 8;
    __shared__ float Bs[LC][DS];
    {
        int t = tid >> 4, n = tid & 15;
        Bs[t][n] = xdbl[(size_t)(b * LSEQ + c * LC + t) * GXP + RANK + n];
    }
    __syncthreads();
    float Av[8];
    float a1 = -__expf(A_log[d * 16]);
    bool fast = true;
#pragma unroll
    for (int j = 0; j < 8; ++j){
        Av[j] = -__expf(A_log[d * 16 + n0 + j]);
        fast = fast && (fabsf(Av[j] - (float)(n0 + j + 1) * a1) <= 1e-4f * fabsf(Av[j]) + 1e-7f);
    }
    float ap[8], ac[8];
#pragma unroll
    for (int j = 0; j < 8; ++j){ ap[j] = 1.f; ac[j] = 0.f; }
    const __hip_bfloat16* dp = delta + (size_t)(b * LSEQ + c * LC) * DIN + d;
    const __hip_bfloat16* xp = xc    + (size_t)(b * LSEQ + c * LC) * DIN + d;
    if (fast){
        for (int t = 0; t < LC; ++t){
            float de = b2f(dp[(size_t)t * DIN]);
            float u  = de * b2f(xp[(size_t)t * DIN]);
            float p  = __expf(de * a1);
            float p2 = p * p, p4 = p2 * p2, p8 = p4 * p4;
            float da = nh ? p8 * p : p;
#pragma unroll
            for (int j = 0; j < 8; ++j){
                ap[j] *= da;
                ac[j] = da * ac[j] + u * Bs[t][n0 + j];
                da *= p;
            }
        }
    } else {
        for (int t = 0; t < LC; ++t){
            float de = b2f(dp[(size_t)t * DIN]);
            float u  = de * b2f(xp[(size_t)t * DIN]);
#pragma unroll
            for (int j = 0; j < 8; ++j){
                float da = __expf(de * Av[j]);
                ap[j] *= da;
                ac[j] = da * ac[j] + u * Bs[t][n0 + j];
            }
        }
    }
    size_t o = (size_t)c * (BSZ * DIN * 16) + (size_t)(b * DIN + d) * 16 + n0;
    *(float4*)(Acar + o)     = make_float4(ap[0], ap[1], ap[2], ap[3]);
    *(float4*)(Acar + o + 4) = make_float4(ap[4], ap[5], ap[6], ap[7]);
    *(float4*)(Bcar + o)     = make_float4(ac[0], ac[1], ac[2], ac[3]);
    *(float4*)(Bcar + o + 4) = make_float4(ac[4], ac[5], ac[6], ac[7]);
}

// ---------------- scan pass 2: prefix over chunks (unroll x4, batched loads) ----------------
__global__ __launch_bounds__(128) void k_scan2(const float* __restrict__ Acar,
                                               const float* __restrict__ Bcar,
                                               float* __restrict__ hinit){
    int idx = blockIdx.x * 128 + threadIdx.x;   // B*DIN*16 = 16384
    const int STRIDE = BSZ * DIN * 16;
    float h = 0.f;
    for (int c = 0; c < NC; c += 4){
        size_t o0 = (size_t)c * STRIDE + idx;
        float a0 = Acar[o0], b0 = Bcar[o0];
        float a1 = Acar[o0 + STRIDE], b1 = Bcar[o0 + STRIDE];
        float a2 = Acar[o0 + 2 * STRIDE], b2 = Bcar[o0 + 2 * STRIDE];
        float a3 = Acar[o0 + 3 * STRIDE], b3 = Bcar[o0 + 3 * STRIDE];
        hinit[o0] = h;               h = a0 * h + b0;
        hinit[o0 + STRIDE] = h;      h = a1 * h + b1;
        hinit[o0 + 2 * STRIDE] = h;  h = a2 * h + b2;
        hinit[o0 + 3 * STRIDE] = h;  h = a3 * h + b3;
    }
}

// ---------------- scan pass 3: replay (n-split x2) + fused (y + D*xc)*silu(z), bf16 out ----------------
__global__ __launch_bounds__(512) void k_scan3(const __hip_bfloat16* __restrict__ delta,
                                               const __hip_bfloat16* __restrict__ xc,
                                               const __hip_bfloat16* __restrict__ xz,
                                               const float* __restrict__ xdbl,
                                               const float* __restrict__ A_log,
                                               const float* __restrict__ D_ssm,
                                               const float* __restrict__ hinit,
                                               __hip_bfloat16* __restrict__ y){
    int bx = blockIdx.x;
    int dh = bx & 1;
    int c  = (bx >> 1) & (NC - 1);
    int b  = bx >> 8;
    int tid = threadIdx.x;
    int dloc = tid >> 1, nh = tid & 1;
    int d = dh * 256 + dloc;
    int n0 = nh * 8;
    __shared__ float Bs[LC][DS], Cs[LC][DS];
    {
        int t = tid >> 4, n = tid & 15;
        size_t r = (size_t)(b * LSEQ + c * LC + t) * GXP;
        Bs[t][n] = xdbl[r + RANK + n];
        Cs[t][n] = xdbl[r + RANK + DS + n];
    }
    __syncthreads();
    float Av[8];
    float a1 = -__expf(A_log[d * 16]);
    bool fast = true;
#pragma unroll
    for (int j = 0; j < 8; ++j){
        Av[j] = -__expf(A_log[d * 16 + n0 + j]);
        fast = fast && (fabsf(Av[j] - (float)(n0 + j + 1) * a1) <= 1e-4f * fabsf(Av[j]) + 1e-7f);
    }
    float h[8];
    size_t ho = (size_t)c * (BSZ * DIN * 16) + (size_t)(b * DIN + d) * 16 + n0;
    {
        float4 h0 = *(const float4*)(hinit + ho);
        float4 h1 = *(const float4*)(hinit + ho + 4);
        h[0] = h0.x; h[1] = h0.y; h[2] = h0.z; h[3] = h0.w;
        h[4] = h1.x; h[5] = h1.y; h[6] = h1.z; h[7] = h1.w;
    }
    float Dd = D_ssm[d];
    size_t rb = (size_t)(b * LSEQ + c * LC);
    if (fast){
        for (int t = 0; t < LC; ++t){
            size_t row = rb + t;
            float de  = b2f(delta[row * DIN + d]);
            float xcv = b2f(xc[row * DIN + d]);
            float u = de * xcv;
            float p  = __expf(de * a1);
            float p2 = p * p, p4 = p2 * p2, p8 = p4 * p4;
            float da = nh ? p8 * p : p;
            float yv = 0.f;
#pragma unroll
            for (int j = 0; j < 8; ++j){
                h[j] = da * h[j] + u * Bs[t][n0 + j];
                yv += h[j] * Cs[t][n0 + j];
                da *= p;
            }
            yv += __shfl_xor(yv, 1);
            if (nh == 0){
                float zv = b2f(xz[row * DXZ + DIN + d]);
                y[row * DIN + d] = f2b((yv + Dd * xcv) * silu_f(zv));
            }
        }
    } else {
        for (int t = 0; t < LC; ++t){
            size_t row = rb + t;
            float de  = b2f(delta[row * DIN + d]);
            float xcv = b2f(xc[row * DIN + d]);
            float u = de * xcv;
            float yv = 0.f;
#pragma unroll
            for (int j = 0; j < 8; ++j){
                float da = __expf(de * Av[j]);
                h[j] = da * h[j] + u * Bs[t][n0 + j];
                yv += h[j] * Cs[t][n0 + j];
            }
            yv += __shfl_xor(yv, 1);
            if (nh == 0){
                float zv = b2f(xz[row * DXZ + DIN + d]);
                y[row * DIN + d] = f2b((yv + Dd * xcv) * silu_f(zv));
            }
        }
    }
}

// ---------------- 3x depthwise "same" conv + SiLU + xssm, write Acomb cols 0..255 bf16 ----------------
__global__ __launch_bounds__(256) void k_msconv(const __hip_bfloat16* __restrict__ xnb,  // Acomb+256, stride 512
                                                const __hip_bfloat16* __restrict__ xssm, // stride 256
                                                const float* __restrict__ c1w, const float* __restrict__ c1b,
                                                const float* __restrict__ c2w, const float* __restrict__ c2b,
                                                const float* __restrict__ c3w, const float* __restrict__ c3b,
                                                __hip_bfloat16* __restrict__ Acomb){     // stride 512
    int idx = blockIdx.x * 256 + threadIdx.x;   // B*L*DM
    int cch = idx & (DM - 1);
    int bl  = idx >> 8;
    int l   = bl & (LSEQ - 1);
    int bL  = bl - l;
    float a1 = c1b[cch], a2 = c2b[cch], a3 = c3b[cch];
#pragma unroll
    for (int j = -3; j <= 3; ++j){
        int ll = l + j;
        if ((unsigned)ll < LSEQ){
            float v = b2f(xnb[(size_t)(bL + ll) * 512 + cch]);
            if (j >= -1 && j <= 1) a1 += c1w[cch * 3 + (j + 1)] * v;
            if (j >= -2 && j <= 2) a2 += c2w[cch * 5 + (j + 2)] * v;
            a3 += c3w[cch * 7 + (j + 3)] * v;
        }
    }
    float res = b2f(xssm[(size_t)bl * 256 + cch]) + silu_f(a1) + silu_f(a2) + silu_f(a3);
    Acomb[(size_t)bl * 512 + cch] = f2b(res);
}

// ---------------- final transpose + residual ----------------
__global__ __launch_bounds__(256) void k_out(const float* __restrict__ outlc,
                                             const float* __restrict__ x,
                                             float* __restrict__ out){
    __shared__ float tile[32][33];
    int bid = blockIdx.x;
    int lt = bid & 127;
    int ct = (bid >> 7) & 7;
    int b  = bid >> 10;
    int l0 = lt * 32, c0 = ct * 32;
    int tx = threadIdx.x & 31, ty = threadIdx.x >> 5;
    for (int r = 0; r < 32; r += 8)
        tile[ty + r][tx] = outlc[(size_t)(b * LSEQ + l0 + ty + r) * DM + c0 + tx];
    __syncthreads();
    for (int r = 0; r < 32; r += 8){
        int cc = c0 + ty + r;
        size_t o = (size_t)(b * DM + cc) * LSEQ + l0 + tx;
        out[o] = tile[tx][ty + r] + x[o];
    }
}

extern "C" void kernel_launch(void* const* d_in, const int* in_sizes, int n_in,
                              void* d_out, int out_size, void* d_ws, size_t ws_size,
                              hipStream_t stream){
    const float* x      = (const float*)d_in[0];
    const float* ln_w   = (const float*)d_in[1];
    const float* ln_b   = (const float*)d_in[2];
    const float* W_in   = (const float*)d_in[3];
    const float* conv_w = (const float*)d_in[4];
    const float* conv_b = (const float*)d_in[5];
    const float* W_xproj= (const float*)d_in[6];
    const float* W_dt   = (const float*)d_in[7];
    const float* b_dt   = (const float*)d_in[8];
    const float* A_log  = (const float*)d_in[9];
    const float* D_ssm  = (const float*)d_in[10];
    const float* W_outp = (const float*)d_in[11];
    const float* c1_w   = (const float*)d_in[12];
    const float* c1_b   = (const float*)d_in[13];
    const float* c2_w   = (const float*)d_in[14];
    const float* c2_b   = (const float*)d_in[15];
    const float* c3_w   = (const float*)d_in[16];
    const float* c3_b   = (const float*)d_in[17];
    const float* W_out  = (const float*)d_in[18];
    const float* b_out  = (const float*)d_in[19];
    const float* W_skip = (const float*)d_in[20];
    const float* b_skip = (const float*)d_in[21];
    float* out = (float*)d_out;

    char* base = (char*)d_ws;
    const size_t MB = 1024 * 1024;
    __hip_bfloat16* Acomb = (__hip_bfloat16*)(base);            // [8192][512]  8 MB
    __hip_bfloat16* xzb   = (__hip_bfloat16*)(base + 8*MB);     // [8192][1024] 16 MB
    __hip_bfloat16* xcb   = (__hip_bfloat16*)(base + 24*MB);    // [8192][512]  8 MB
    float*          xdbl  = (float*)        (base + 32*MB);     // [8192][48]   1.5 MB
    __hip_bfloat16* deltab= (__hip_bfloat16*)(base + 34*MB);    // [8192][512]  8 MB
    float*          Acar  = (float*)        (base + 42*MB);     // 8 MB  (NC=128)
    float*          Bcar  = (float*)        (base + 50*MB);     // 8 MB
    float*          hinit = (float*)        (base + 58*MB);     // 8 MB
    __hip_bfloat16* xssmb = (__hip_bfloat16*)(base + 66*MB);    // [8192][256]  4 MB
    __hip_bfloat16* Winb  = (__hip_bfloat16*)(base + 70*MB);    // 512 KB
    __hip_bfloat16* Wxpb  = (__hip_bfloat16*)(base + 70*MB + 512*1024);   // 64 KB
    __hip_bfloat16* Wopb  = (__hip_bfloat16*)(base + 71*MB);    // 256 KB
    __hip_bfloat16* Wcb   = (__hip_bfloat16*)(base + 71*MB + 256*1024);   // 256 KB
    float*          bc    = (float*)        (base + 71*MB + 512*1024);    // 1 KB
    __hip_bfloat16* xnb   = Acomb + 256;                        // stride 512
    __hip_bfloat16* ybf   = (__hip_bfloat16*)Bcar;              // alias: Bcar dead after scan2 (8 MB)
    float*          outlc = Acar;                               // alias: Acar dead after scan2 (8 MB)

    const int M = BSZ * LSEQ;   // 8192

    k_cvtw<<<dim3(256), dim3(256), 0, stream>>>(W_in, W_xproj, W_outp, W_out, W_skip, b_out, b_skip,
                                                Winb, Wxpb, Wopb, Wcb, bc);
    k_ln<<<dim3(256), dim3(256), 0, stream>>>(x, ln_w, ln_b, xnb);
    // xz = xn @ W_in^T               M=8192 N=1024 K=256
    k_mgemm<8><<<dim3(64, 16), dim3(256), 0, stream>>>(xnb, 512, Winb, nullptr, xzb, DXZ, 1024, 256);
    k_conv<<<dim3(M * DIN / 4 / 256), dim3(256), 0, stream>>>(xzb, conv_w, conv_b, xcb);
    // xdbl = xc @ W_xproj^T          M=8192 N=48 K=512  (f32 out)
    k_mgemm<0><<<dim3(64, 1), dim3(256), 0, stream>>>(xcb, 512, Wxpb, nullptr, xdbl, GXP, GXP, 512);
    // delta = softplus(xdbl @ W_dt^T + b_dt)
    k_dtgemm<<<dim3(128, 8), dim3(256), 0, stream>>>(xdbl, GXP, W_dt, b_dt, deltab, DIN);
    k_scan1<<<dim3(BSZ * NC * 2), dim3(512), 0, stream>>>(deltab, xcb, xdbl, A_log, Acar, Bcar);
    k_scan2<<<dim3(128), dim3(128), 0, stream>>>(Acar, Bcar, hinit);
    k_scan3<<<dim3(BSZ * NC * 2), dim3(512), 0, stream>>>(deltab, xcb, xzb, xdbl, A_log, D_ssm, hinit, ybf);
    // xssm = y @ W_outp^T            M=8192 N=256 K=512 (bf16 out)
    k_mgemm<8><<<dim3(64, 4), dim3(256), 0, stream>>>(ybf, 512, Wopb, nullptr, xssmb, 256, 256, 512);
    k_msconv<<<dim3(M * DM / 256), dim3(256), 0, stream>>>(xnb, xssmb, c1_w, c1_b, c2_w, c2_b, c3_w, c3_b, Acomb);
    // outlc = [xssm|xn] @ [W_out|W_skip]^T + (b_out+b_skip)   M=8192 N=256 K=512 (f32 out)
    k_mgemm<1><<<dim3(64, 4), dim3(256), 0, stream>>>(Acomb, 512, Wcb, bc, outlc, DM, 256, 512);
    k_out<<<dim3(2048), dim3(256), 0, stream>>>(outlc, x, out);
}

// Round 6
// 250.197 us; speedup vs baseline: 1.8186x; 1.0373x over previous
//
#include <hip/hip_runtime.h>
#include <hip/hip_bf16.h>
#include <math.h>
#include <cstddef>

#define BSZ 2
#define DM 256
#define LSEQ 4096
#define DIN 512
#define DXZ 1024
#define DS 16
#define RANK 16
#define GXP 48
#define LC 32
#define NC 128   // LSEQ / LC
#define CSTRIDE (BSZ * DIN * 16)   // 16384 sequences

typedef __attribute__((ext_vector_type(8))) short short8;
typedef __attribute__((ext_vector_type(4))) float f32x4;
struct bf4 { __hip_bfloat16 v[4]; };

__device__ __forceinline__ float silu_f(float x){ return x / (1.f + __expf(-x)); }
__device__ __forceinline__ float softplus_f(float x){ return fmaxf(x, 0.f) + log1pf(__expf(-fabsf(x))); }
__device__ __forceinline__ float b2f(__hip_bfloat16 v){ return __bfloat162float(v); }
__device__ __forceinline__ __hip_bfloat16 f2b(float v){ return __float2bfloat16(v); }

__device__ __forceinline__ void gl_lds16(const void* g, void* s){
    __builtin_amdgcn_global_load_lds((const __attribute__((address_space(1))) void*)g,
                                     (__attribute__((address_space(3))) void*)s, 16, 0, 0);
}

// ---------------- LayerNorm + transpose (B,C,L) -> (B,L,C) bf16, into Acomb cols 256..511 ----------------
__global__ __launch_bounds__(256) void k_ln(const float* __restrict__ x,
                                            const float* __restrict__ lnw,
                                            const float* __restrict__ lnb,
                                            __hip_bfloat16* __restrict__ xnb){   // stride 512, already offset +256
    __shared__ float tile[DM * 33];
    __shared__ float rsum[8][32], rsq[8][32];
    __shared__ float mu_s[32], rs_s[32];
    int b  = blockIdx.x >> 7;
    int l0 = (blockIdx.x & 127) << 5;
    int tid = threadIdx.x;
    const float* xb = x + (size_t)b * DM * LSEQ;
    int lls = tid & 31, chi = tid >> 5;
    for (int cc = 0; cc < 32; ++cc){
        int c = cc * 8 + chi;
        tile[c * 33 + lls] = xb[(size_t)c * LSEQ + l0 + lls];
    }
    __syncthreads();
    int part = tid >> 5, l = tid & 31;
    float s = 0.f, sq = 0.f;
    for (int i = 0; i < 32; ++i){
        float v = tile[(part * 32 + i) * 33 + l];
        s += v; sq += v * v;
    }
    rsum[part][l] = s; rsq[part][l] = sq;
    __syncthreads();
    if (tid < 32){
        float ts = 0.f, tq = 0.f;
        for (int p = 0; p < 8; ++p){ ts += rsum[p][tid]; tq += rsq[p][tid]; }
        float mu  = ts * (1.f / DM);
        float var = tq * (1.f / DM) - mu * mu;
        mu_s[tid] = mu;
        rs_s[tid] = rsqrtf(var + 1e-5f);
    }
    __syncthreads();
    int c0 = tid & 63, lh = tid >> 6;
    for (int i = 0; i < 8; ++i){
        int ll = lh + 4 * i;
        float mu = mu_s[ll], rs = rs_s[ll];
        __hip_bfloat16* orow = xnb + (size_t)(b * LSEQ + l0 + ll) * 512;
        for (int j = 0; j < 4; ++j){
            int c = c0 + 64 * j;
            orow[c] = f2b((tile[c * 33 + ll] - mu) * rs * lnw[c] + lnb[c]);
        }
    }
}

// ---------------- weight conversion f32 -> bf16 (+pad/fuse) ----------------
__global__ __launch_bounds__(256) void k_cvtw(const float* __restrict__ W_in, const float* __restrict__ W_xproj,
                                              const float* __restrict__ W_outp, const float* __restrict__ W_out,
                                              const float* __restrict__ W_skip, const float* __restrict__ b_out,
                                              const float* __restrict__ b_skip,
                                              __hip_bfloat16* __restrict__ Winb, __hip_bfloat16* __restrict__ Wxpb,
                                              __hip_bfloat16* __restrict__ Wopb, __hip_bfloat16* __restrict__ Wcb,
                                              float* __restrict__ bc){
    int i0 = blockIdx.x * 256 + threadIdx.x;
    const int T = 256 * 256;
    for (int j = i0; j < 1024 * 256; j += T) Winb[j] = f2b(W_in[j]);
    for (int j = i0; j < 64 * 512; j += T){
        int r = j >> 9;
        Wxpb[j] = f2b(r < GXP ? W_xproj[r * 512 + (j & 511)] : 0.f);
    }
    for (int j = i0; j < 256 * 512; j += T) Wopb[j] = f2b(W_outp[j]);
    for (int j = i0; j < 256 * 512; j += T){
        int n = j >> 9, k = j & 511;
        Wcb[j] = f2b(k < 256 ? W_out[n * 256 + k] : W_skip[n * 256 + (k - 256)]);
    }
    if (i0 < 256) bc[i0] = b_out[i0] + b_skip[i0];
}

// ---------------- bf16 MFMA GEMM: C[M][ldc] = A[M][lda-strided] @ W[N][K]^T ----------------
// tile BMx64, BK=64, 256 thr = 4 waves (2M x 2N), 16x16x32 MFMA
// EPI: 1 = +bias, 8 = bf16 output.  BM in {128, 32}.
template<int EPI, int BM = 128>
__global__ __launch_bounds__(256) void k_mgemm(const __hip_bfloat16* __restrict__ A, int lda,
                                               const __hip_bfloat16* __restrict__ W,
                                               const float* __restrict__ bias,
                                               void* __restrict__ Cv, int ldc,
                                               int N, int K){
    constexpr int SA = BM / 8;        // A segments (8 rows x 64 cols each)
    constexpr int SAW = SA / 4;       // A segments per wave
    constexpr int WROWS = BM / 2;     // rows per wave (2 waves in M)
    constexpr int MI = WROWS / 16;    // 16-row frags per wave
    __shared__ __align__(16) __hip_bfloat16 As[BM * 64];
    __shared__ __align__(16) __hip_bfloat16 Ws[64 * 64];
    const int tid = threadIdx.x;
    const int wave = tid >> 6, lane = tid & 63;
    const int brow = blockIdx.x * BM, bcol = blockIdx.y * 64;
    const int wm = wave >> 1, wn = wave & 1;

    const int a_row = lane >> 3;          // 0..7 within segment
    const int a_chk = lane & 7;           // 16B chunk within row
    const int a_scol = ((a_chk ^ a_row) * 8);   // swizzled source column (elements)

    const int lrow = lane & 15;
    const int kc = lane >> 4;             // 0..3
    const int r7 = lrow & 7;

    f32x4 acc[MI][2] = {};

    for (int k0 = 0; k0 < K; k0 += 64){
#pragma unroll
        for (int j = 0; j < SAW; ++j){
            int seg = wave * SAW + j;
            const __hip_bfloat16* src = A + (size_t)(brow + seg * 8 + a_row) * lda + k0 + a_scol;
            gl_lds16(src, &As[seg * 512]);
        }
#pragma unroll
        for (int j = 0; j < 2; ++j){
            int seg = wave * 2 + j;
            const __hip_bfloat16* src = W + (size_t)(bcol + seg * 8 + a_row) * K + k0 + a_scol;
            gl_lds16(src, &Ws[seg * 512]);
        }
        __syncthreads();
#pragma unroll
        for (int kk = 0; kk < 2; ++kk){
            int kchunk = kk * 4 + kc;
            short8 af[MI], bfr[2];
#pragma unroll
            for (int mi = 0; mi < MI; ++mi){
                int row = wm * WROWS + mi * 16 + lrow;
                af[mi] = *(const short8*)&As[row * 64 + ((kchunk ^ r7) * 8)];
            }
#pragma unroll
            for (int ni = 0; ni < 2; ++ni){
                int row = wn * 32 + ni * 16 + lrow;
                bfr[ni] = *(const short8*)&Ws[row * 64 + ((kchunk ^ r7) * 8)];
            }
#pragma unroll
            for (int mi = 0; mi < MI; ++mi)
#pragma unroll
                for (int ni = 0; ni < 2; ++ni)
                    acc[mi][ni] = __builtin_amdgcn_mfma_f32_16x16x32_bf16(af[mi], bfr[ni], acc[mi][ni], 0, 0, 0);
        }
        __syncthreads();
    }

#pragma unroll
    for (int ni = 0; ni < 2; ++ni){
        int n = bcol + wn * 32 + ni * 16 + lrow;
        if (n >= N) continue;
        float bv = (EPI & 1) ? bias[n] : 0.f;
#pragma unroll
        for (int mi = 0; mi < MI; ++mi){
            int m0 = brow + wm * WROWS + mi * 16 + kc * 4;
#pragma unroll
            for (int r = 0; r < 4; ++r){
                float v = acc[mi][ni][r] + bv;
                if (EPI & 8) ((__hip_bfloat16*)Cv)[(size_t)(m0 + r) * ldc + n] = f2b(v);
                else         ((float*)Cv)[(size_t)(m0 + r) * ldc + n] = v;
            }
        }
    }
}

// ---------------- f32 GEMM for delta (K=16): delta = softplus(xdbl[:, :16] @ W_dt^T + b_dt), bf16 out ----------------
__global__ __launch_bounds__(256) void k_dtgemm(const float* __restrict__ A, int lda,
                                                const float* __restrict__ Wt,
                                                const float* __restrict__ bias,
                                                __hip_bfloat16* __restrict__ C, int ldc){
    __shared__ float As[16][68];
    __shared__ float Ws[16][68];
    int bm = blockIdx.x * 64, bn = blockIdx.y * 64;
    int tid = threadIdx.x;
    int a_m = tid >> 2, a_k = (tid & 3) * 4;
    int tx = tid & 15, ty = tid >> 4;
    float acc[4][4] = {};
    {
        float4 av = *(const float4*)(A + (size_t)(bm + a_m) * lda + a_k);
        As[a_k + 0][a_m] = av.x; As[a_k + 1][a_m] = av.y;
        As[a_k + 2][a_m] = av.z; As[a_k + 3][a_m] = av.w;
        float4 wv = *(const float4*)(Wt + (size_t)(bn + a_m) * 16 + a_k);
        Ws[a_k + 0][a_m] = wv.x; Ws[a_k + 1][a_m] = wv.y;
        Ws[a_k + 2][a_m] = wv.z; Ws[a_k + 3][a_m] = wv.w;
        __syncthreads();
#pragma unroll
        for (int k = 0; k < 16; ++k){
            float4 a4 = *(const float4*)&As[k][ty * 4];
            float4 b4 = *(const float4*)&Ws[k][tx * 4];
            acc[0][0] += a4.x * b4.x; acc[0][1] += a4.x * b4.y; acc[0][2] += a4.x * b4.z; acc[0][3] += a4.x * b4.w;
            acc[1][0] += a4.y * b4.x; acc[1][1] += a4.y * b4.y; acc[1][2] += a4.y * b4.z; acc[1][3] += a4.y * b4.w;
            acc[2][0] += a4.z * b4.x; acc[2][1] += a4.z * b4.y; acc[2][2] += a4.z * b4.z; acc[2][3] += a4.z * b4.w;
            acc[3][0] += a4.w * b4.x; acc[3][1] += a4.w * b4.y; acc[3][2] += a4.w * b4.z; acc[3][3] += a4.w * b4.w;
        }
    }
    int n = bn + tx * 4;
    float4 bb = *(const float4*)(bias + n);
#pragma unroll
    for (int i = 0; i < 4; ++i){
        int m = bm + ty * 4 + i;
        __hip_bfloat16* cp = C + (size_t)m * ldc + n;
        cp[0] = f2b(softplus_f(acc[i][0] + bb.x));
        cp[1] = f2b(softplus_f(acc[i][1] + bb.y));
        cp[2] = f2b(softplus_f(acc[i][2] + bb.z));
        cp[3] = f2b(softplus_f(acc[i][3] + bb.w));
    }
}

// ---------------- causal depthwise conv k=4 + SiLU (bf16 in/out, 4-wide) ----------------
__global__ __launch_bounds__(256) void k_conv(const __hip_bfloat16* __restrict__ xz,
                                              const float* __restrict__ cw,
                                              const float* __restrict__ cb,
                                              __hip_bfloat16* __restrict__ xc){
    int idx = blockIdx.x * 256 + threadIdx.x;   // B*L*DIN/4
    int d4 = (idx & 127) * 4;
    int bl = idx >> 7;
    int l  = bl & (LSEQ - 1);
    const __hip_bfloat16* base = xz + (size_t)bl * DXZ + d4;
    float4 bias = *(const float4*)(cb + d4);
    float acc[4] = {bias.x, bias.y, bias.z, bias.w};
    float4 w0 = *(const float4*)(cw + (d4 + 0) * 4);
    float4 w1 = *(const float4*)(cw + (d4 + 1) * 4);
    float4 w2 = *(const float4*)(cw + (d4 + 2) * 4);
    float4 w3 = *(const float4*)(cw + (d4 + 3) * 4);
    const float* wj[4] = {(const float*)&w0, (const float*)&w1, (const float*)&w2, (const float*)&w3};
#pragma unroll
    for (int t = 0; t < 4; ++t){
        int ls = l - (3 - t);
        if (ls >= 0){
            bf4 v = *(const bf4*)(base - (size_t)(3 - t) * DXZ);
#pragma unroll
            for (int j = 0; j < 4; ++j) acc[j] += wj[j][t] * b2f(v.v[j]);
        }
    }
    bf4 o;
#pragma unroll
    for (int j = 0; j < 4; ++j) o.v[j] = f2b(silu_f(acc[j]));
    *(bf4*)(xc + (size_t)bl * DIN + d4) = o;
}

// ---------------- scan pass 1: per-chunk carries, n-split x2 ----------------
// grid: [b(1b) | c(7b) | dh(1b)]; block 512: dloc = tid>>1, nh = tid&1
__global__ __launch_bounds__(512) void k_scan1(const __hip_bfloat16* __restrict__ delta,
                                               const __hip_bfloat16* __restrict__ xc,
                                               const float* __restrict__ xdbl,
                                               const float* __restrict__ A_log,
                                               float* __restrict__ Acar,
                                               float* __restrict__ Bcar){
    int bx = blockIdx.x;
    int dh = bx & 1;
    int c  = (bx >> 1) & (NC - 1);
    int b  = bx >> 8;
    int tid = threadIdx.x;
    int dloc = tid >> 1, nh = tid & 1;
    int d = dh * 256 + dloc;
    int n0 = nh * 8;
    __shared__ float Bs[LC][DS];
    {
        int t = tid >> 4, n = tid & 15;
        Bs[t][n] = xdbl[(size_t)(b * LSEQ + c * LC + t) * GXP + RANK + n];
    }
    __syncthreads();
    float Av[8];
    float a1 = -__expf(A_log[d * 16]);
    bool fast = true;
#pragma unroll
    for (int j = 0; j < 8; ++j){
        Av[j] = -__expf(A_log[d * 16 + n0 + j]);
        fast = fast && (fabsf(Av[j] - (float)(n0 + j + 1) * a1) <= 1e-4f * fabsf(Av[j]) + 1e-7f);
    }
    float ap[8], ac[8];
#pragma unroll
    for (int j = 0; j < 8; ++j){ ap[j] = 1.f; ac[j] = 0.f; }
    const __hip_bfloat16* dp = delta + (size_t)(b * LSEQ + c * LC) * DIN + d;
    const __hip_bfloat16* xp = xc    + (size_t)(b * LSEQ + c * LC) * DIN + d;
    if (fast){
        for (int t = 0; t < LC; ++t){
            float de = b2f(dp[(size_t)t * DIN]);
            float u  = de * b2f(xp[(size_t)t * DIN]);
            float p  = __expf(de * a1);
            float p2 = p * p, p4 = p2 * p2, p8 = p4 * p4;
            float da = nh ? p8 * p : p;
#pragma unroll
            for (int j = 0; j < 8; ++j){
                ap[j] *= da;
                ac[j] = da * ac[j] + u * Bs[t][n0 + j];
                da *= p;
            }
        }
    } else {
        for (int t = 0; t < LC; ++t){
            float de = b2f(dp[(size_t)t * DIN]);
            float u  = de * b2f(xp[(size_t)t * DIN]);
#pragma unroll
            for (int j = 0; j < 8; ++j){
                float da = __expf(de * Av[j]);
                ap[j] *= da;
                ac[j] = da * ac[j] + u * Bs[t][n0 + j];
            }
        }
    }
    size_t o = (size_t)c * CSTRIDE + (size_t)(b * DIN + d) * 16 + n0;
    *(float4*)(Acar + o)     = make_float4(ap[0], ap[1], ap[2], ap[3]);
    *(float4*)(Acar + o + 4) = make_float4(ap[4], ap[5], ap[6], ap[7]);
    *(float4*)(Bcar + o)     = make_float4(ac[0], ac[1], ac[2], ac[3]);
    *(float4*)(Bcar + o + 4) = make_float4(ac[4], ac[5], ac[6], ac[7]);
}

// ---------------- scan pass 2: wave-parallel Kogge-Stone prefix over 128 chunks ----------------
// grid 512 x 256 thr. Block handles 32 sequences; each wave scans one sequence (64 lane-pairs).
// op (a,b): h -> a*h + b.  compose(X first, Y second) = (ax*ay, ay*bx + by).
__global__ __launch_bounds__(256) void k_scan2(const float* __restrict__ Acar,
                                               const float* __restrict__ Bcar,
                                               float* __restrict__ hinit){
    __shared__ float a_s[NC][33];
    __shared__ float b_s[NC][33];
    __shared__ float h_s[NC][33];
    const int tid = threadIdx.x;
    const int idx0 = blockIdx.x * 32;
    const int s_ld = tid & 31, cr = tid >> 5;   // load/store geometry: 8 c-rows per pass
#pragma unroll
    for (int r = 0; r < 16; ++r){
        int c = r * 8 + cr;
        size_t g = (size_t)c * CSTRIDE + idx0 + s_ld;
        a_s[c][s_ld] = Acar[g];
        b_s[c][s_ld] = Bcar[g];
    }
    __syncthreads();
    const int lane = tid & 63, w = tid >> 6;
#pragma unroll
    for (int i = 0; i < 8; ++i){
        int s = w * 8 + i;
        float a0 = a_s[2 * lane][s],     b0 = b_s[2 * lane][s];
        float a1 = a_s[2 * lane + 1][s], b1 = b_s[2 * lane + 1][s];
        float av = a0 * a1, bv = a1 * b0 + b1;          // own pair = e(2l) then e(2l+1)
#pragma unroll
        for (int d2 = 1; d2 < 64; d2 <<= 1){
            float ao = __shfl_up(av, d2);
            float bo = __shfl_up(bv, d2);
            if (lane >= d2){ bv = av * bo + bv; av = ao * av; }
        }
        float ax = __shfl_up(av, 1), bx = __shfl_up(bv, 1);   // exclusive
        if (lane == 0){ ax = 1.f; bx = 0.f; }
        h_s[2 * lane][s]     = bx;                // h at chunk 2l  (applied to h0=0)
        h_s[2 * lane + 1][s] = a0 * bx + b0;      // excl ∘ e(2l)
    }
    __syncthreads();
#pragma unroll
    for (int r = 0; r < 16; ++r){
        int c = r * 8 + cr;
        hinit[(size_t)c * CSTRIDE + idx0 + s_ld] = h_s[c][s_ld];
    }
}

// ---------------- scan pass 3: replay (n-split x2) + fused (y + D*xc)*silu(z), bf16 out ----------------
__global__ __launch_bounds__(512) void k_scan3(const __hip_bfloat16* __restrict__ delta,
                                               const __hip_bfloat16* __restrict__ xc,
                                               const __hip_bfloat16* __restrict__ xz,
                                               const float* __restrict__ xdbl,
                                               const float* __restrict__ A_log,
                                               const float* __restrict__ D_ssm,
                                               const float* __restrict__ hinit,
                                               __hip_bfloat16* __restrict__ y){
    int bx = blockIdx.x;
    int dh = bx & 1;
    int c  = (bx >> 1) & (NC - 1);
    int b  = bx >> 8;
    int tid = threadIdx.x;
    int dloc = tid >> 1, nh = tid & 1;
    int d = dh * 256 + dloc;
    int n0 = nh * 8;
    __shared__ float Bs[LC][DS], Cs[LC][DS];
    {
        int t = tid >> 4, n = tid & 15;
        size_t r = (size_t)(b * LSEQ + c * LC + t) * GXP;
        Bs[t][n] = xdbl[r + RANK + n];
        Cs[t][n] = xdbl[r + RANK + DS + n];
    }
    __syncthreads();
    float Av[8];
    float a1 = -__expf(A_log[d * 16]);
    bool fast = true;
#pragma unroll
    for (int j = 0; j < 8; ++j){
        Av[j] = -__expf(A_log[d * 16 + n0 + j]);
        fast = fast && (fabsf(Av[j] - (float)(n0 + j + 1) * a1) <= 1e-4f * fabsf(Av[j]) + 1e-7f);
    }
    float h[8];
    size_t ho = (size_t)c * CSTRIDE + (size_t)(b * DIN + d) * 16 + n0;
    {
        float4 h0 = *(const float4*)(hinit + ho);
        float4 h1 = *(const float4*)(hinit + ho + 4);
        h[0] = h0.x; h[1] = h0.y; h[2] = h0.z; h[3] = h0.w;
        h[4] = h1.x; h[5] = h1.y; h[6] = h1.z; h[7] = h1.w;
    }
    float Dd = D_ssm[d];
    size_t rb = (size_t)(b * LSEQ + c * LC);
    if (fast){
        for (int t = 0; t < LC; ++t){
            size_t row = rb + t;
            float de  = b2f(delta[row * DIN + d]);
            float xcv = b2f(xc[row * DIN + d]);
            float u = de * xcv;
            float p  = __expf(de * a1);
            float p2 = p * p, p4 = p2 * p2, p8 = p4 * p4;
            float da = nh ? p8 * p : p;
            float yv = 0.f;
#pragma unroll
            for (int j = 0; j < 8; ++j){
                h[j] = da * h[j] + u * Bs[t][n0 + j];
                yv += h[j] * Cs[t][n0 + j];
                da *= p;
            }
            yv += __shfl_xor(yv, 1);
            if (nh == 0){
                float zv = b2f(xz[row * DXZ + DIN + d]);
                y[row * DIN + d] = f2b((yv + Dd * xcv) * silu_f(zv));
            }
        }
    } else {
        for (int t = 0; t < LC; ++t){
            size_t row = rb + t;
            float de  = b2f(delta[row * DIN + d]);
            float xcv = b2f(xc[row * DIN + d]);
            float u = de * xcv;
            float yv = 0.f;
#pragma unroll
            for (int j = 0; j < 8; ++j){
                float da = __expf(de * Av[j]);
                h[j] = da * h[j] + u * Bs[t][n0 + j];
                yv += h[j] * Cs[t][n0 + j];
            }
            yv += __shfl_xor(yv, 1);
            if (nh == 0){
                float zv = b2f(xz[row * DXZ + DIN + d]);
                y[row * DIN + d] = f2b((yv + Dd * xcv) * silu_f(zv));
            }
        }
    }
}

// ---------------- 3x depthwise "same" conv + SiLU + xssm, write Acomb cols 0..255 bf16 ----------------
__global__ __launch_bounds__(256) void k_msconv(const __hip_bfloat16* __restrict__ xnb,  // Acomb+256, stride 512
                                                const __hip_bfloat16* __restrict__ xssm, // stride 256
                                                const float* __restrict__ c1w, const float* __restrict__ c1b,
                                                const float* __restrict__ c2w, const float* __restrict__ c2b,
                                                const float* __restrict__ c3w, const float* __restrict__ c3b,
                                                __hip_bfloat16* __restrict__ Acomb){     // stride 512
    int idx = blockIdx.x * 256 + threadIdx.x;   // B*L*DM
    int cch = idx & (DM - 1);
    int bl  = idx >> 8;
    int l   = bl & (LSEQ - 1);
    int bL  = bl - l;
    float a1 = c1b[cch], a2 = c2b[cch], a3 = c3b[cch];
#pragma unroll
    for (int j = -3; j <= 3; ++j){
        int ll = l + j;
        if ((unsigned)ll < LSEQ){
            float v = b2f(xnb[(size_t)(bL + ll) * 512 + cch]);
            if (j >= -1 && j <= 1) a1 += c1w[cch * 3 + (j + 1)] * v;
            if (j >= -2 && j <= 2) a2 += c2w[cch * 5 + (j + 2)] * v;
            a3 += c3w[cch * 7 + (j + 3)] * v;
        }
    }
    float res = b2f(xssm[(size_t)bl * 256 + cch]) + silu_f(a1) + silu_f(a2) + silu_f(a3);
    Acomb[(size_t)bl * 512 + cch] = f2b(res);
}

// ---------------- final transpose + residual ----------------
__global__ __launch_bounds__(256) void k_out(const float* __restrict__ outlc,
                                             const float* __restrict__ x,
                                             float* __restrict__ out){
    __shared__ float tile[32][33];
    int bid = blockIdx.x;
    int lt = bid & 127;
    int ct = (bid >> 7) & 7;
    int b  = bid >> 10;
    int l0 = lt * 32, c0 = ct * 32;
    int tx = threadIdx.x & 31, ty = threadIdx.x >> 5;
    for (int r = 0; r < 32; r += 8)
        tile[ty + r][tx] = outlc[(size_t)(b * LSEQ + l0 + ty + r) * DM + c0 + tx];
    __syncthreads();
    for (int r = 0; r < 32; r += 8){
        int cc = c0 + ty + r;
        size_t o = (size_t)(b * DM + cc) * LSEQ + l0 + tx;
        out[o] = tile[tx][ty + r] + x[o];
    }
}

extern "C" void kernel_launch(void* const* d_in, const int* in_sizes, int n_in,
                              void* d_out, int out_size, void* d_ws, size_t ws_size,
                              hipStream_t stream){
    const float* x      = (const float*)d_in[0];
    const float* ln_w   = (const float*)d_in[1];
    const float* ln_b   = (const float*)d_in[2];
    const float* W_in   = (const float*)d_in[3];
    const float* conv_w = (const float*)d_in[4];
    const float* conv_b = (const float*)d_in[5];
    const float* W_xproj= (const float*)d_in[6];
    const float* W_dt   = (const float*)d_in[7];
    const float* b_dt   = (const float*)d_in[8];
    const float* A_log  = (const float*)d_in[9];
    const float* D_ssm  = (const float*)d_in[10];
    const float* W_outp = (const float*)d_in[11];
    const float* c1_w   = (const float*)d_in[12];
    const float* c1_b   = (const float*)d_in[13];
    const float* c2_w   = (const float*)d_in[14];
    const float* c2_b   = (const float*)d_in[15];
    const float* c3_w   = (const float*)d_in[16];
    const float* c3_b   = (const float*)d_in[17];
    const float* W_out  = (const float*)d_in[18];
    const float* b_out  = (const float*)d_in[19];
    const float* W_skip = (const float*)d_in[20];
    const float* b_skip = (const float*)d_in[21];
    float* out = (float*)d_out;

    char* base = (char*)d_ws;
    const size_t MB = 1024 * 1024;
    __hip_bfloat16* Acomb = (__hip_bfloat16*)(base);            // [8192][512]  8 MB
    __hip_bfloat16* xzb   = (__hip_bfloat16*)(base + 8*MB);     // [8192][1024] 16 MB
    __hip_bfloat16* xcb   = (__hip_bfloat16*)(base + 24*MB);    // [8192][512]  8 MB
    float*          xdbl  = (float*)        (base + 32*MB);     // [8192][48]   1.5 MB
    __hip_bfloat16* deltab= (__hip_bfloat16*)(base + 34*MB);    // [8192][512]  8 MB
    float*          Acar  = (float*)        (base + 42*MB);     // 8 MB  (NC=128)
    float*          Bcar  = (float*)        (base + 50*MB);     // 8 MB
    float*          hinit = (float*)        (base + 58*MB);     // 8 MB
    __hip_bfloat16* xssmb = (__hip_bfloat16*)(base + 66*MB);    // [8192][256]  4 MB
    __hip_bfloat16* Winb  = (__hip_bfloat16*)(base + 70*MB);    // 512 KB
    __hip_bfloat16* Wxpb  = (__hip_bfloat16*)(base + 70*MB + 512*1024);   // 64 KB
    __hip_bfloat16* Wopb  = (__hip_bfloat16*)(base + 71*MB);    // 256 KB
    __hip_bfloat16* Wcb   = (__hip_bfloat16*)(base + 71*MB + 256*1024);   // 256 KB
    float*          bc    = (float*)        (base + 71*MB + 512*1024);    // 1 KB
    __hip_bfloat16* xnb   = Acomb + 256;                        // stride 512
    __hip_bfloat16* ybf   = (__hip_bfloat16*)Bcar;              // alias: Bcar dead after scan2 (8 MB)
    float*          outlc = Acar;                               // alias: Acar dead after scan2 (8 MB)

    const int M = BSZ * LSEQ;   // 8192

    k_cvtw<<<dim3(256), dim3(256), 0, stream>>>(W_in, W_xproj, W_outp, W_out, W_skip, b_out, b_skip,
                                                Winb, Wxpb, Wopb, Wcb, bc);
    k_ln<<<dim3(256), dim3(256), 0, stream>>>(x, ln_w, ln_b, xnb);
    // xz = xn @ W_in^T               M=8192 N=1024 K=256
    k_mgemm<8><<<dim3(64, 16), dim3(256), 0, stream>>>(xnb, 512, Winb, nullptr, xzb, DXZ, 1024, 256);
    k_conv<<<dim3(M * DIN / 4 / 256), dim3(256), 0, stream>>>(xzb, conv_w, conv_b, xcb);
    // xdbl = xc @ W_xproj^T          M=8192 N=48 K=512  (f32 out, BM=32 -> 256 blocks)
    k_mgemm<0, 32><<<dim3(256, 1), dim3(256), 0, stream>>>(xcb, 512, Wxpb, nullptr, xdbl, GXP, GXP, 512);
    // delta = softplus(xdbl @ W_dt^T + b_dt)
    k_dtgemm<<<dim3(128, 8), dim3(256), 0, stream>>>(xdbl, GXP, W_dt, b_dt, deltab, DIN);
    k_scan1<<<dim3(BSZ * NC * 2), dim3(512), 0, stream>>>(deltab, xcb, xdbl, A_log, Acar, Bcar);
    k_scan2<<<dim3(512), dim3(256), 0, stream>>>(Acar, Bcar, hinit);
    k_scan3<<<dim3(BSZ * NC * 2), dim3(512), 0, stream>>>(deltab, xcb, xzb, xdbl, A_log, D_ssm, hinit, ybf);
    // xssm = y @ W_outp^T            M=8192 N=256 K=512 (bf16 out)
    k_mgemm<8><<<dim3(64, 4), dim3(256), 0, stream>>>(ybf, 512, Wopb, nullptr, xssmb, 256, 256, 512);
    k_msconv<<<dim3(M * DM / 256), dim3(256), 0, stream>>>(xnb, xssmb, c1_w, c1_b, c2_w, c2_b, c3_w, c3_b, Acomb);
    // outlc = [xssm|xn] @ [W_out|W_skip]^T + (b_out+b_skip)   M=8192 N=256 K=512 (f32 out)
    k_mgemm<1><<<dim3(64, 4), dim3(256), 0, stream>>>(Acomb, 512, Wcb, bc, outlc, DM, 256, 512);
    k_out<<<dim3(2048), dim3(256), 0, stream>>>(outlc, x, out);
}

// Round 8
// 244.720 us; speedup vs baseline: 1.8593x; 1.0224x over previous
//
#include <hip/hip_runtime.h>
#include <hip/hip_bf16.h>
#include <math.h>
#include <cstddef>

#define BSZ 2
#define DM 256
#define LSEQ 4096
#define DIN 512
#define DXZ 1024
#define DS 16
#define RANK 16
#define GXP 48
#define LC 32
#define NC 128   // LSEQ / LC
#define CSTRIDE (BSZ * DIN * 16)   // 16384 sequences

typedef __attribute__((ext_vector_type(8))) short short8;
typedef __attribute__((ext_vector_type(4))) float f32x4;
struct bf4 { __hip_bfloat16 v[4]; };

__device__ __forceinline__ float silu_f(float x){ return x / (1.f + __expf(-x)); }
__device__ __forceinline__ float softplus_f(float x){ return fmaxf(x, 0.f) + log1pf(__expf(-fabsf(x))); }
__device__ __forceinline__ float b2f(__hip_bfloat16 v){ return __bfloat162float(v); }
__device__ __forceinline__ __hip_bfloat16 f2b(float v){ return __float2bfloat16(v); }

__device__ __forceinline__ void gl_lds16(const void* g, void* s){
    __builtin_amdgcn_global_load_lds((const __attribute__((address_space(1))) void*)g,
                                     (__attribute__((address_space(3))) void*)s, 16, 0, 0);
}

// ---------------- LayerNorm + transpose (B,C,L) -> (B,L,C) bf16, into Acomb cols 256..511 ----------------
__global__ __launch_bounds__(256) void k_ln(const float* __restrict__ x,
                                            const float* __restrict__ lnw,
                                            const float* __restrict__ lnb,
                                            __hip_bfloat16* __restrict__ xnb){   // stride 512, already offset +256
    __shared__ float tile[DM * 33];
    __shared__ float rsum[8][32], rsq[8][32];
    __shared__ float mu_s[32], rs_s[32];
    int b  = blockIdx.x >> 7;
    int l0 = (blockIdx.x & 127) << 5;
    int tid = threadIdx.x;
    const float* xb = x + (size_t)b * DM * LSEQ;
    int lls = tid & 31, chi = tid >> 5;
    for (int cc = 0; cc < 32; ++cc){
        int c = cc * 8 + chi;
        tile[c * 33 + lls] = xb[(size_t)c * LSEQ + l0 + lls];
    }
    __syncthreads();
    int part = tid >> 5, l = tid & 31;
    float s = 0.f, sq = 0.f;
    for (int i = 0; i < 32; ++i){
        float v = tile[(part * 32 + i) * 33 + l];
        s += v; sq += v * v;
    }
    rsum[part][l] = s; rsq[part][l] = sq;
    __syncthreads();
    if (tid < 32){
        float ts = 0.f, tq = 0.f;
        for (int p = 0; p < 8; ++p){ ts += rsum[p][tid]; tq += rsq[p][tid]; }
        float mu  = ts * (1.f / DM);
        float var = tq * (1.f / DM) - mu * mu;
        mu_s[tid] = mu;
        rs_s[tid] = rsqrtf(var + 1e-5f);
    }
    __syncthreads();
    int c0 = tid & 63, lh = tid >> 6;
    for (int i = 0; i < 8; ++i){
        int ll = lh + 4 * i;
        float mu = mu_s[ll], rs = rs_s[ll];
        __hip_bfloat16* orow = xnb + (size_t)(b * LSEQ + l0 + ll) * 512;
        for (int j = 0; j < 4; ++j){
            int c = c0 + 64 * j;
            orow[c] = f2b((tile[c * 33 + ll] - mu) * rs * lnw[c] + lnb[c]);
        }
    }
}

// ---------------- weight conversion f32 -> bf16 (+pad/fuse) ----------------
__global__ __launch_bounds__(256) void k_cvtw(const float* __restrict__ W_in, const float* __restrict__ W_xproj,
                                              const float* __restrict__ W_outp, const float* __restrict__ W_out,
                                              const float* __restrict__ W_skip, const float* __restrict__ b_out,
                                              const float* __restrict__ b_skip,
                                              __hip_bfloat16* __restrict__ Winb, __hip_bfloat16* __restrict__ Wxpb,
                                              __hip_bfloat16* __restrict__ Wopb, __hip_bfloat16* __restrict__ Wcb,
                                              float* __restrict__ bc){
    int i0 = blockIdx.x * 256 + threadIdx.x;
    const int T = 256 * 256;
    for (int j = i0; j < 1024 * 256; j += T) Winb[j] = f2b(W_in[j]);
    for (int j = i0; j < 64 * 512; j += T){
        int r = j >> 9;
        Wxpb[j] = f2b(r < GXP ? W_xproj[r * 512 + (j & 511)] : 0.f);
    }
    for (int j = i0; j < 256 * 512; j += T) Wopb[j] = f2b(W_outp[j]);
    for (int j = i0; j < 256 * 512; j += T){
        int n = j >> 9, k = j & 511;
        Wcb[j] = f2b(k < 256 ? W_out[n * 256 + k] : W_skip[n * 256 + (k - 256)]);
    }
    if (i0 < 256) bc[i0] = b_out[i0] + b_skip[i0];
}

// ---------------- bf16 MFMA GEMM: C[M][ldc] = A[M][lda-strided] @ W[N][K]^T ----------------
// tile BMxBN, BK=64, 256 thr = 4 waves (2M x 2N), 16x16x32 MFMA
// EPI: 1 = +bias, 8 = bf16 output, 16 = fused transpose+residual to out[B][C][L] (uses xres; implies bias)
template<int EPI, int BM = 128, int BN = 64>
__global__ __launch_bounds__(256) void k_mgemm(const __hip_bfloat16* __restrict__ A, int lda,
                                               const __hip_bfloat16* __restrict__ W,
                                               const float* __restrict__ bias,
                                               void* __restrict__ Cv, int ldc,
                                               int N, int K,
                                               const float* __restrict__ xres = nullptr){
    constexpr int SA  = BM / 8;       // A segments (8 rows x 64 cols each)
    constexpr int SAW = SA / 4;       // A segments per wave
    constexpr int SB  = BN / 8;       // W segments
    constexpr int SBW = SB / 4;       // W segments per wave
    constexpr int WROWS = BM / 2;     // rows per wave (2 waves in M)
    constexpr int WCOLS = BN / 2;     // cols per wave (2 waves in N)
    constexpr int MI = WROWS / 16;
    constexpr int NI = WCOLS / 16;
    __shared__ __align__(16) __hip_bfloat16 As[BM * 64];
    __shared__ __align__(16) __hip_bfloat16 Ws[BN * 64];
    __shared__ float tileT[(EPI & 16) ? 64 * 65 : 1];
    const int tid = threadIdx.x;
    const int wave = tid >> 6, lane = tid & 63;
    const int brow = blockIdx.x * BM, bcol = blockIdx.y * BN;
    const int wm = wave >> 1, wn = wave & 1;

    const int a_row = lane >> 3;          // 0..7 within segment
    const int a_chk = lane & 7;           // 16B chunk within row
    const int a_scol = ((a_chk ^ a_row) * 8);   // swizzled source column (elements)

    const int lrow = lane & 15;
    const int kc = lane >> 4;             // 0..3
    const int r7 = lrow & 7;

    f32x4 acc[MI][NI] = {};

    for (int k0 = 0; k0 < K; k0 += 64){
#pragma unroll
        for (int j = 0; j < SAW; ++j){
            int seg = wave * SAW + j;
            const __hip_bfloat16* src = A + (size_t)(brow + seg * 8 + a_row) * lda + k0 + a_scol;
            gl_lds16(src, &As[seg * 512]);
        }
#pragma unroll
        for (int j = 0; j < SBW; ++j){
            int seg = wave * SBW + j;
            const __hip_bfloat16* src = W + (size_t)(bcol + seg * 8 + a_row) * K + k0 + a_scol;
            gl_lds16(src, &Ws[seg * 512]);
        }
        __syncthreads();
#pragma unroll
        for (int kk = 0; kk < 2; ++kk){
            int kchunk = kk * 4 + kc;
            short8 af[MI], bfr[NI];
#pragma unroll
            for (int mi = 0; mi < MI; ++mi){
                int row = wm * WROWS + mi * 16 + lrow;
                af[mi] = *(const short8*)&As[row * 64 + ((kchunk ^ r7) * 8)];
            }
#pragma unroll
            for (int ni = 0; ni < NI; ++ni){
                int row = wn * WCOLS + ni * 16 + lrow;
                bfr[ni] = *(const short8*)&Ws[row * 64 + ((kchunk ^ r7) * 8)];
            }
#pragma unroll
            for (int mi = 0; mi < MI; ++mi)
#pragma unroll
                for (int ni = 0; ni < NI; ++ni)
                    acc[mi][ni] = __builtin_amdgcn_mfma_f32_16x16x32_bf16(af[mi], bfr[ni], acc[mi][ni], 0, 0, 0);
        }
        __syncthreads();
    }

    if (EPI & 16){
        // stage C tile [n_local][m_local] into LDS, then coalesced transposed write + bias + residual
#pragma unroll
        for (int ni = 0; ni < NI; ++ni){
            int nl = wn * WCOLS + ni * 16 + lrow;
#pragma unroll
            for (int mi = 0; mi < MI; ++mi){
                int ml = wm * WROWS + mi * 16 + kc * 4;
#pragma unroll
                for (int r = 0; r < 4; ++r)
                    tileT[nl * 65 + ml + r] = acc[mi][ni][r];
            }
        }
        __syncthreads();
        int b = brow >> 12, l0 = brow & 4095;
        int lr = tid & 63, nr = tid >> 6;
        float* out = (float*)Cv;
#pragma unroll
        for (int rr = 0; rr < 16; ++rr){
            int n = rr * 4 + nr;
            size_t o = (size_t)(b * DM + bcol + n) * LSEQ + l0 + lr;
            out[o] = tileT[n * 65 + lr] + bias[bcol + n] + xres[o];
        }
        return;
    }

#pragma unroll
    for (int ni = 0; ni < NI; ++ni){
        int n = bcol + wn * WCOLS + ni * 16 + lrow;
        if (n >= N) continue;
        float bv = (EPI & 1) ? bias[n] : 0.f;
#pragma unroll
        for (int mi = 0; mi < MI; ++mi){
            int m0 = brow + wm * WROWS + mi * 16 + kc * 4;
#pragma unroll
            for (int r = 0; r < 4; ++r){
                float v = acc[mi][ni][r] + bv;
                if (EPI & 8) ((__hip_bfloat16*)Cv)[(size_t)(m0 + r) * ldc + n] = f2b(v);
                else         ((float*)Cv)[(size_t)(m0 + r) * ldc + n] = v;
            }
        }
    }
}

// ---------------- f32 GEMM for delta (K=16): delta = softplus(xdbl[:, :16] @ W_dt^T + b_dt), bf16 out ----------------
__global__ __launch_bounds__(256) void k_dtgemm(const float* __restrict__ A, int lda,
                                                const float* __restrict__ Wt,
                                                const float* __restrict__ bias,
                                                __hip_bfloat16* __restrict__ C, int ldc){
    __shared__ float As[16][68];
    __shared__ float Ws[16][68];
    int bm = blockIdx.x * 64, bn = blockIdx.y * 64;
    int tid = threadIdx.x;
    int a_m = tid >> 2, a_k = (tid & 3) * 4;
    int tx = tid & 15, ty = tid >> 4;
    float acc[4][4] = {};
    {
        float4 av = *(const float4*)(A + (size_t)(bm + a_m) * lda + a_k);
        As[a_k + 0][a_m] = av.x; As[a_k + 1][a_m] = av.y;
        As[a_k + 2][a_m] = av.z; As[a_k + 3][a_m] = av.w;
        float4 wv = *(const float4*)(Wt + (size_t)(bn + a_m) * 16 + a_k);
        Ws[a_k + 0][a_m] = wv.x; Ws[a_k + 1][a_m] = wv.y;
        Ws[a_k + 2][a_m] = wv.z; Ws[a_k + 3][a_m] = wv.w;
        __syncthreads();
#pragma unroll
        for (int k = 0; k < 16; ++k){
            float4 a4 = *(const float4*)&As[k][ty * 4];
            float4 b4 = *(const float4*)&Ws[k][tx * 4];
            acc[0][0] += a4.x * b4.x; acc[0][1] += a4.x * b4.y; acc[0][2] += a4.x * b4.z; acc[0][3] += a4.x * b4.w;
            acc[1][0] += a4.y * b4.x; acc[1][1] += a4.y * b4.y; acc[1][2] += a4.y * b4.z; acc[1][3] += a4.y * b4.w;
            acc[2][0] += a4.z * b4.x; acc[2][1] += a4.z * b4.y; acc[2][2] += a4.z * b4.z; acc[2][3] += a4.z * b4.w;
            acc[3][0] += a4.w * b4.x; acc[3][1] += a4.w * b4.y; acc[3][2] += a4.w * b4.z; acc[3][3] += a4.w * b4.w;
        }
    }
    int n = bn + tx * 4;
    float4 bb = *(const float4*)(bias + n);
#pragma unroll
    for (int i = 0; i < 4; ++i){
        int m = bm + ty * 4 + i;
        __hip_bfloat16* cp = C + (size_t)m * ldc + n;
        cp[0] = f2b(softplus_f(acc[i][0] + bb.x));
        cp[1] = f2b(softplus_f(acc[i][1] + bb.y));
        cp[2] = f2b(softplus_f(acc[i][2] + bb.z));
        cp[3] = f2b(softplus_f(acc[i][3] + bb.w));
    }
}

// ---------------- causal depthwise conv k=4 + SiLU (bf16 in/out, 4-wide) ----------------
__global__ __launch_bounds__(256) void k_conv(const __hip_bfloat16* __restrict__ xz,
                                              const float* __restrict__ cw,
                                              const float* __restrict__ cb,
                                              __hip_bfloat16* __restrict__ xc){
    int idx = blockIdx.x * 256 + threadIdx.x;   // B*L*DIN/4
    int d4 = (idx & 127) * 4;
    int bl = idx >> 7;
    int l  = bl & (LSEQ - 1);
    const __hip_bfloat16* base = xz + (size_t)bl * DXZ + d4;
    float4 bias = *(const float4*)(cb + d4);
    float acc[4] = {bias.x, bias.y, bias.z, bias.w};
    float4 w0 = *(const float4*)(cw + (d4 + 0) * 4);
    float4 w1 = *(const float4*)(cw + (d4 + 1) * 4);
    float4 w2 = *(const float4*)(cw + (d4 + 2) * 4);
    float4 w3 = *(const float4*)(cw + (d4 + 3) * 4);
    const float* wj[4] = {(const float*)&w0, (const float*)&w1, (const float*)&w2, (const float*)&w3};
#pragma unroll
    for (int t = 0; t < 4; ++t){
        int ls = l - (3 - t);
        if (ls >= 0){
            bf4 v = *(const bf4*)(base - (size_t)(3 - t) * DXZ);
#pragma unroll
            for (int j = 0; j < 4; ++j) acc[j] += wj[j][t] * b2f(v.v[j]);
        }
    }
    bf4 o;
#pragma unroll
    for (int j = 0; j < 4; ++j) o.v[j] = f2b(silu_f(acc[j]));
    *(bf4*)(xc + (size_t)bl * DIN + d4) = o;
}

// ---------------- scan pass 1: per-chunk carries, n-split x2 ----------------
__global__ __launch_bounds__(512) void k_scan1(const __hip_bfloat16* __restrict__ delta,
                                               const __hip_bfloat16* __restrict__ xc,
                                               const float* __restrict__ xdbl,
                                               const float* __restrict__ A_log,
                                               float* __restrict__ Acar,
                                               float* __restrict__ Bcar){
    int bx = blockIdx.x;
    int dh = bx & 1;
    int c  = (bx >> 1) & (NC - 1);
    int b  = bx >> 8;
    int tid = threadIdx.x;
    int dloc = tid >> 1, nh = tid & 1;
    int d = dh * 256 + dloc;
    int n0 = nh * 8;
    __shared__ float Bs[LC][DS];
    {
        int t = tid >> 4, n = tid & 15;
        Bs[t][n] = xdbl[(size_t)(b * LSEQ + c * LC + t) * GXP + RANK + n];
    }
    __syncthreads();
    float Av[8];
    float a1 = -__expf(A_log[d * 16]);
    bool fast = true;
#pragma unroll
    for (int j = 0; j < 8; ++j){
        Av[j] = -__expf(A_log[d * 16 + n0 + j]);
        fast = fast && (fabsf(Av[j] - (float)(n0 + j + 1) * a1) <= 1e-4f * fabsf(Av[j]) + 1e-7f);
    }
    float ap[8], ac[8];
#pragma unroll
    for (int j = 0; j < 8; ++j){ ap[j] = 1.f; ac[j] = 0.f; }
    const __hip_bfloat16* dp = delta + (size_t)(b * LSEQ + c * LC) * DIN + d;
    const __hip_bfloat16* xp = xc    + (size_t)(b * LSEQ + c * LC) * DIN + d;
    if (fast){
        for (int t = 0; t < LC; ++t){
            float de = b2f(dp[(size_t)t * DIN]);
            float u  = de * b2f(xp[(size_t)t * DIN]);
            float p  = __expf(de * a1);
            float p2 = p * p, p4 = p2 * p2, p8 = p4 * p4;
            float da = nh ? p8 * p : p;
#pragma unroll
            for (int j = 0; j < 8; ++j){
                ap[j] *= da;
                ac[j] = da * ac[j] + u * Bs[t][n0 + j];
                da *= p;
            }
        }
    } else {
        for (int t = 0; t < LC; ++t){
            float de = b2f(dp[(size_t)t * DIN]);
            float u  = de * b2f(xp[(size_t)t * DIN]);
#pragma unroll
            for (int j = 0; j < 8; ++j){
                float da = __expf(de * Av[j]);
                ap[j] *= da;
                ac[j] = da * ac[j] + u * Bs[t][n0 + j];
            }
        }
    }
    size_t o = (size_t)c * CSTRIDE + (size_t)(b * DIN + d) * 16 + n0;
    *(float4*)(Acar + o)     = make_float4(ap[0], ap[1], ap[2], ap[3]);
    *(float4*)(Acar + o + 4) = make_float4(ap[4], ap[5], ap[6], ap[7]);
    *(float4*)(Bcar + o)     = make_float4(ac[0], ac[1], ac[2], ac[3]);
    *(float4*)(Bcar + o + 4) = make_float4(ac[4], ac[5], ac[6], ac[7]);
}

// ---------------- scan pass 2: wave-parallel Kogge-Stone prefix over 128 chunks ----------------
__global__ __launch_bounds__(256) void k_scan2(const float* __restrict__ Acar,
                                               const float* __restrict__ Bcar,
                                               float* __restrict__ hinit){
    __shared__ float a_s[NC][33];
    __shared__ float b_s[NC][33];
    __shared__ float h_s[NC][33];
    const int tid = threadIdx.x;
    const int idx0 = blockIdx.x * 32;
    const int s_ld = tid & 31, cr = tid >> 5;
#pragma unroll
    for (int r = 0; r < 16; ++r){
        int c = r * 8 + cr;
        size_t g = (size_t)c * CSTRIDE + idx0 + s_ld;
        a_s[c][s_ld] = Acar[g];
        b_s[c][s_ld] = Bcar[g];
    }
    __syncthreads();
    const int lane = tid & 63, w = tid >> 6;
#pragma unroll
    for (int i = 0; i < 8; ++i){
        int s = w * 8 + i;
        float a0 = a_s[2 * lane][s],     b0 = b_s[2 * lane][s];
        float a1 = a_s[2 * lane + 1][s], b1 = b_s[2 * lane + 1][s];
        float av = a0 * a1, bv = a1 * b0 + b1;
#pragma unroll
        for (int d2 = 1; d2 < 64; d2 <<= 1){
            float ao = __shfl_up(av, d2);
            float bo = __shfl_up(bv, d2);
            if (lane >= d2){ bv = av * bo + bv; av = ao * av; }
        }
        float ax = __shfl_up(av, 1), bx = __shfl_up(bv, 1);
        if (lane == 0){ ax = 1.f; bx = 0.f; }
        h_s[2 * lane][s]     = bx;
        h_s[2 * lane + 1][s] = a0 * bx + b0;
    }
    __syncthreads();
#pragma unroll
    for (int r = 0; r < 16; ++r){
        int c = r * 8 + cr;
        hinit[(size_t)c * CSTRIDE + idx0 + s_ld] = h_s[c][s_ld];
    }
}

// ---------------- scan pass 3: replay (n-split x2) + fused (y + D*xc)*silu(z), bf16 out ----------------
__global__ __launch_bounds__(512) void k_scan3(const __hip_bfloat16* __restrict__ delta,
                                               const __hip_bfloat16* __restrict__ xc,
                                               const __hip_bfloat16* __restrict__ xz,
                                               const float* __restrict__ xdbl,
                                               const float* __restrict__ A_log,
                                               const float* __restrict__ D_ssm,
                                               const float* __restrict__ hinit,
                                               __hip_bfloat16* __restrict__ y){
    int bx = blockIdx.x;
    int dh = bx & 1;
    int c  = (bx >> 1) & (NC - 1);
    int b  = bx >> 8;
    int tid = threadIdx.x;
    int dloc = tid >> 1, nh = tid & 1;
    int d = dh * 256 + dloc;
    int n0 = nh * 8;
    __shared__ float Bs[LC][DS], Cs[LC][DS];
    {
        int t = tid >> 4, n = tid & 15;
        size_t r = (size_t)(b * LSEQ + c * LC + t) * GXP;
        Bs[t][n] = xdbl[r + RANK + n];
        Cs[t][n] = xdbl[r + RANK + DS + n];
    }
    __syncthreads();
    float Av[8];
    float a1 = -__expf(A_log[d * 16]);
    bool fast = true;
#pragma unroll
    for (int j = 0; j < 8; ++j){
        Av[j] = -__expf(A_log[d * 16 + n0 + j]);
        fast = fast && (fabsf(Av[j] - (float)(n0 + j + 1) * a1) <= 1e-4f * fabsf(Av[j]) + 1e-7f);
    }
    float h[8];
    size_t ho = (size_t)c * CSTRIDE + (size_t)(b * DIN + d) * 16 + n0;
    {
        float4 h0 = *(const float4*)(hinit + ho);
        float4 h1 = *(const float4*)(hinit + ho + 4);
        h[0] = h0.x; h[1] = h0.y; h[2] = h0.z; h[3] = h0.w;
        h[4] = h1.x; h[5] = h1.y; h[6] = h1.z; h[7] = h1.w;
    }
    float Dd = D_ssm[d];
    size_t rb = (size_t)(b * LSEQ + c * LC);
    if (fast){
        for (int t = 0; t < LC; ++t){
            size_t row = rb + t;
            float de  = b2f(delta[row * DIN + d]);
            float xcv = b2f(xc[row * DIN + d]);
            float u = de * xcv;
            float p  = __expf(de * a1);
            float p2 = p * p, p4 = p2 * p2, p8 = p4 * p4;
            float da = nh ? p8 * p : p;
            float yv = 0.f;
#pragma unroll
            for (int j = 0; j < 8; ++j){
                h[j] = da * h[j] + u * Bs[t][n0 + j];
                yv += h[j] * Cs[t][n0 + j];
                da *= p;
            }
            yv += __shfl_xor(yv, 1);
            if (nh == 0){
                float zv = b2f(xz[row * DXZ + DIN + d]);
                y[row * DIN + d] = f2b((yv + Dd * xcv) * silu_f(zv));
            }
        }
    } else {
        for (int t = 0; t < LC; ++t){
            size_t row = rb + t;
            float de  = b2f(delta[row * DIN + d]);
            float xcv = b2f(xc[row * DIN + d]);
            float u = de * xcv;
            float yv = 0.f;
#pragma unroll
            for (int j = 0; j < 8; ++j){
                float da = __expf(de * Av[j]);
                h[j] = da * h[j] + u * Bs[t][n0 + j];
                yv += h[j] * Cs[t][n0 + j];
            }
            yv += __shfl_xor(yv, 1);
            if (nh == 0){
                float zv = b2f(xz[row * DXZ + DIN + d]);
                y[row * DIN + d] = f2b((yv + Dd * xcv) * silu_f(zv));
            }
        }
    }
}

// ---------------- 3x depthwise "same" conv + SiLU + xssm, write Acomb cols 0..255 bf16 ----------------
__global__ __launch_bounds__(256) void k_msconv(const __hip_bfloat16* __restrict__ xnb,  // Acomb+256, stride 512
                                                const __hip_bfloat16* __restrict__ xssm, // stride 256
                                                const float* __restrict__ c1w, const float* __restrict__ c1b,
                                                const float* __restrict__ c2w, const float* __restrict__ c2b,
                                                const float* __restrict__ c3w, const float* __restrict__ c3b,
                                                __hip_bfloat16* __restrict__ Acomb){     // stride 512
    int idx = blockIdx.x * 256 + threadIdx.x;   // B*L*DM
    int cch = idx & (DM - 1);
    int bl  = idx >> 8;
    int l   = bl & (LSEQ - 1);
    int bL  = bl - l;
    float a1 = c1b[cch], a2 = c2b[cch], a3 = c3b[cch];
#pragma unroll
    for (int j = -3; j <= 3; ++j){
        int ll = l + j;
        if ((unsigned)ll < LSEQ){
            float v = b2f(xnb[(size_t)(bL + ll) * 512 + cch]);
            if (j >= -1 && j <= 1) a1 += c1w[cch * 3 + (j + 1)] * v;
            if (j >= -2 && j <= 2) a2 += c2w[cch * 5 + (j + 2)] * v;
            a3 += c3w[cch * 7 + (j + 3)] * v;
        }
    }
    float res = b2f(xssm[(size_t)bl * 256 + cch]) + silu_f(a1) + silu_f(a2) + silu_f(a3);
    Acomb[(size_t)bl * 512 + cch] = f2b(res);
}

extern "C" void kernel_launch(void* const* d_in, const int* in_sizes, int n_in,
                              void* d_out, int out_size, void* d_ws, size_t ws_size,
                              hipStream_t stream){
    const float* x      = (const float*)d_in[0];
    const float* ln_w   = (const float*)d_in[1];
    const float* ln_b   = (const float*)d_in[2];
    const float* W_in   = (const float*)d_in[3];
    const float* conv_w = (const float*)d_in[4];
    const float* conv_b = (const float*)d_in[5];
    const float* W_xproj= (const float*)d_in[6];
    const float* W_dt   = (const float*)d_in[7];
    const float* b_dt   = (const float*)d_in[8];
    const float* A_log  = (const float*)d_in[9];
    const float* D_ssm  = (const float*)d_in[10];
    const float* W_outp = (const float*)d_in[11];
    const float* c1_w   = (const float*)d_in[12];
    const float* c1_b   = (const float*)d_in[13];
    const float* c2_w   = (const float*)d_in[14];
    const float* c2_b   = (const float*)d_in[15];
    const float* c3_w   = (const float*)d_in[16];
    const float* c3_b   = (const float*)d_in[17];
    const float* W_out  = (const float*)d_in[18];
    const float* b_out  = (const float*)d_in[19];
    const float* W_skip = (const float*)d_in[20];
    const float* b_skip = (const float*)d_in[21];
    float* out = (float*)d_out;

    char* base = (char*)d_ws;
    const size_t MB = 1024 * 1024;
    __hip_bfloat16* Acomb = (__hip_bfloat16*)(base);            // [8192][512]  8 MB
    __hip_bfloat16* xzb   = (__hip_bfloat16*)(base + 8*MB);     // [8192][1024] 16 MB
    __hip_bfloat16* xcb   = (__hip_bfloat16*)(base + 24*MB);    // [8192][512]  8 MB
    float*          xdbl  = (float*)        (base + 32*MB);     // [8192][48]   1.5 MB
    __hip_bfloat16* deltab= (__hip_bfloat16*)(base + 34*MB);    // [8192][512]  8 MB
    float*          Acar  = (float*)        (base + 42*MB);     // 8 MB  (NC=128)
    float*          Bcar  = (float*)        (base + 50*MB);     // 8 MB
    float*          hinit = (float*)        (base + 58*MB);     // 8 MB
    __hip_bfloat16* xssmb = (__hip_bfloat16*)(base + 66*MB);    // [8192][256]  4 MB
    __hip_bfloat16* Winb  = (__hip_bfloat16*)(base + 70*MB);    // 512 KB
    __hip_bfloat16* Wxpb  = (__hip_bfloat16*)(base + 70*MB + 512*1024);   // 64 KB
    __hip_bfloat16* Wopb  = (__hip_bfloat16*)(base + 71*MB);    // 256 KB
    __hip_bfloat16* Wcb   = (__hip_bfloat16*)(base + 71*MB + 256*1024);   // 256 KB
    float*          bc    = (float*)        (base + 71*MB + 512*1024);    // 1 KB
    __hip_bfloat16* xnb   = Acomb + 256;                        // stride 512
    __hip_bfloat16* ybf   = (__hip_bfloat16*)Bcar;              // alias: Bcar dead after scan2 (8 MB)

    const int M = BSZ * LSEQ;   // 8192

    k_cvtw<<<dim3(256), dim3(256), 0, stream>>>(W_in, W_xproj, W_outp, W_out, W_skip, b_out, b_skip,
                                                Winb, Wxpb, Wopb, Wcb, bc);
    k_ln<<<dim3(256), dim3(256), 0, stream>>>(x, ln_w, ln_b, xnb);
    // xz = xn @ W_in^T               M=8192 N=1024 K=256   (128x128 tile, 512 blocks)
    k_mgemm<8, 128, 128><<<dim3(64, 8), dim3(256), 0, stream>>>(xnb, 512, Winb, nullptr, xzb, DXZ, 1024, 256);
    k_conv<<<dim3(M * DIN / 4 / 256), dim3(256), 0, stream>>>(xzb, conv_w, conv_b, xcb);
    // xdbl = xc @ W_xproj^T          M=8192 N=48 K=512  (f32 out, BM=32 -> 256 blocks)
    k_mgemm<0, 32, 64><<<dim3(256, 1), dim3(256), 0, stream>>>(xcb, 512, Wxpb, nullptr, xdbl, GXP, GXP, 512);
    // delta = softplus(xdbl @ W_dt^T + b_dt)
    k_dtgemm<<<dim3(128, 8), dim3(256), 0, stream>>>(xdbl, GXP, W_dt, b_dt, deltab, DIN);
    k_scan1<<<dim3(BSZ * NC * 2), dim3(512), 0, stream>>>(deltab, xcb, xdbl, A_log, Acar, Bcar);
    k_scan2<<<dim3(512), dim3(256), 0, stream>>>(Acar, Bcar, hinit);
    k_scan3<<<dim3(BSZ * NC * 2), dim3(512), 0, stream>>>(deltab, xcb, xzb, xdbl, A_log, D_ssm, hinit, ybf);
    // xssm = y @ W_outp^T            M=8192 N=256 K=512 (bf16 out, BM=64 -> 512 blocks)
    k_mgemm<8, 64, 64><<<dim3(128, 4), dim3(256), 0, stream>>>(ybf, 512, Wopb, nullptr, xssmb, 256, 256, 512);
    k_msconv<<<dim3(M * DM / 256), dim3(256), 0, stream>>>(xnb, xssmb, c1_w, c1_b, c2_w, c2_b, c3_w, c3_b, Acomb);
    // out = transpose([xssm|xn] @ [W_out|W_skip]^T + bc) + x   (fused epilogue, BM=64 -> 512 blocks)
    k_mgemm<17, 64, 64><<<dim3(128, 4), dim3(256), 0, stream>>>(Acomb, 512, Wcb, bc, out, DM, 256, 512, x);
}

// Round 9
// 232.486 us; speedup vs baseline: 1.9571x; 1.0526x over previous
//
#include <hip/hip_runtime.h>
#include <hip/hip_bf16.h>
#include <math.h>
#include <cstddef>

#define BSZ 2
#define DM 256
#define LSEQ 4096
#define DIN 512
#define DXZ 1024
#define DS 16
#define RANK 16
#define GXP 48
#define LC 32
#define NC 128   // LSEQ / LC
#define CSTRIDE (BSZ * DIN * 16)   // 16384 sequences

typedef __attribute__((ext_vector_type(8))) short short8;
typedef __attribute__((ext_vector_type(4))) float f32x4;
struct bf4 { __hip_bfloat16 v[4]; };

__device__ __forceinline__ float silu_f(float x){ return x / (1.f + __expf(-x)); }
__device__ __forceinline__ float softplus_f(float x){ return fmaxf(x, 0.f) + log1pf(__expf(-fabsf(x))); }
__device__ __forceinline__ float b2f(__hip_bfloat16 v){ return __bfloat162float(v); }
__device__ __forceinline__ __hip_bfloat16 f2b(float v){ return __float2bfloat16(v); }

__device__ __forceinline__ void gl_lds16(const void* g, void* s){
    __builtin_amdgcn_global_load_lds((const __attribute__((address_space(1))) void*)g,
                                     (__attribute__((address_space(3))) void*)s, 16, 0, 0);
}

// ---------------- fused: LayerNorm-transpose (blocks 0-255) + weight cvt/pack (blocks 256-511) ----------------
__global__ __launch_bounds__(256) void k_pre(const float* __restrict__ x,
                                             const float* __restrict__ lnw, const float* __restrict__ lnb,
                                             const float* __restrict__ W_in, const float* __restrict__ W_xproj,
                                             const float* __restrict__ W_outp, const float* __restrict__ W_out,
                                             const float* __restrict__ W_skip, const float* __restrict__ b_out,
                                             const float* __restrict__ b_skip, const float* __restrict__ W_dt,
                                             const float* __restrict__ c1w, const float* __restrict__ c1b,
                                             const float* __restrict__ c2w, const float* __restrict__ c2b,
                                             const float* __restrict__ c3w, const float* __restrict__ c3b,
                                             __hip_bfloat16* __restrict__ xnb,
                                             __hip_bfloat16* __restrict__ Winb, __hip_bfloat16* __restrict__ Wxpb,
                                             __hip_bfloat16* __restrict__ Wopb, __hip_bfloat16* __restrict__ Wcb,
                                             __hip_bfloat16* __restrict__ Wdtb, float* __restrict__ bc,
                                             float* __restrict__ msw){
    __shared__ float tile[DM * 33];
    __shared__ float rsum[8][32], rsq[8][32];
    __shared__ float mu_s[32], rs_s[32];
    int tid = threadIdx.x;
    if (blockIdx.x < 256){
        int b  = blockIdx.x >> 7;
        int l0 = (blockIdx.x & 127) << 5;
        const float* xb = x + (size_t)b * DM * LSEQ;
        int lls = tid & 31, chi = tid >> 5;
        for (int cc = 0; cc < 32; ++cc){
            int c = cc * 8 + chi;
            tile[c * 33 + lls] = xb[(size_t)c * LSEQ + l0 + lls];
        }
        __syncthreads();
        int part = tid >> 5, l = tid & 31;
        float s = 0.f, sq = 0.f;
        for (int i = 0; i < 32; ++i){
            float v = tile[(part * 32 + i) * 33 + l];
            s += v; sq += v * v;
        }
        rsum[part][l] = s; rsq[part][l] = sq;
        __syncthreads();
        if (tid < 32){
            float ts = 0.f, tq = 0.f;
            for (int p = 0; p < 8; ++p){ ts += rsum[p][tid]; tq += rsq[p][tid]; }
            float mu  = ts * (1.f / DM);
            float var = tq * (1.f / DM) - mu * mu;
            mu_s[tid] = mu;
            rs_s[tid] = rsqrtf(var + 1e-5f);
        }
        __syncthreads();
        int c0 = tid & 63, lh = tid >> 6;
        for (int i = 0; i < 8; ++i){
            int ll = lh + 4 * i;
            float mu = mu_s[ll], rs = rs_s[ll];
            __hip_bfloat16* orow = xnb + (size_t)(b * LSEQ + l0 + ll) * 512;
            for (int j = 0; j < 4; ++j){
                int c = c0 + 64 * j;
                orow[c] = f2b((tile[c * 33 + ll] - mu) * rs * lnw[c] + lnb[c]);
            }
        }
    } else {
        int i0 = (blockIdx.x - 256) * 256 + tid;
        const int T = 256 * 256;
        for (int j = i0; j < 1024 * 256; j += T) Winb[j] = f2b(W_in[j]);
        for (int j = i0; j < 64 * 512; j += T){
            int r = j >> 9;
            Wxpb[j] = f2b(r < GXP ? W_xproj[r * 512 + (j & 511)] : 0.f);
        }
        for (int j = i0; j < 256 * 512; j += T) Wopb[j] = f2b(W_outp[j]);
        for (int j = i0; j < 256 * 512; j += T){
            int n = j >> 9, k = j & 511;
            Wcb[j] = f2b(k < 256 ? W_out[n * 256 + k] : W_skip[n * 256 + (k - 256)]);
        }
        for (int j = i0; j < 512 * 32; j += T){
            int n = j >> 5, k = j & 31;
            Wdtb[j] = f2b(k < 16 ? W_dt[n * 16 + k] : 0.f);
        }
        if (i0 < 256){
            bc[i0] = b_out[i0] + b_skip[i0];
            float* m = msw + i0 * 20;
            m[0] = c1w[i0*3]; m[1] = c1w[i0*3+1]; m[2] = c1w[i0*3+2];
            for (int j = 0; j < 5; ++j) m[3+j] = c2w[i0*5+j];
            for (int j = 0; j < 7; ++j) m[8+j] = c3w[i0*7+j];
            m[15] = c1b[i0]; m[16] = c2b[i0]; m[17] = c3b[i0];
            m[18] = 0.f; m[19] = 0.f;
        }
    }
}

// ---------------- bf16 MFMA GEMM: C[M][ldc] = A[M][lda-strided] @ W[N][K]^T ----------------
// tile BMxBN, BK=64, 256 thr = 4 waves (2M x 2N), 16x16x32 MFMA
// EPI: 1 = +bias, 8 = bf16 out, 16 = fused transpose+residual to out[B][C][L] (xres),
//      32 = fused msconv epilogue (xnb2 + msw) -> bf16 Acomb
template<int EPI, int BM = 128, int BN = 64>
__global__ __launch_bounds__(256) void k_mgemm(const __hip_bfloat16* __restrict__ A, int lda,
                                               const __hip_bfloat16* __restrict__ W,
                                               const float* __restrict__ bias,
                                               void* __restrict__ Cv, int ldc,
                                               int N, int K,
                                               const float* __restrict__ xres = nullptr,
                                               const __hip_bfloat16* __restrict__ xnb2 = nullptr,
                                               const float* __restrict__ msw = nullptr){
    constexpr int SA  = BM / 8;
    constexpr int SAW = SA / 4;
    constexpr int SB  = BN / 8;
    constexpr int SBW = SB / 4;
    constexpr int WROWS = BM / 2;
    constexpr int WCOLS = BN / 2;
    constexpr int MI = WROWS / 16;
    constexpr int NI = WCOLS / 16;
    __shared__ __align__(16) __hip_bfloat16 As[BM * 64];
    __shared__ __align__(16) __hip_bfloat16 Ws[BN * 64];
    __shared__ float tileT[(EPI & 16) ? 64 * 65 : 1];
    const int tid = threadIdx.x;
    const int wave = tid >> 6, lane = tid & 63;
    const int brow = blockIdx.x * BM, bcol = blockIdx.y * BN;
    const int wm = wave >> 1, wn = wave & 1;

    const int a_row = lane >> 3;
    const int a_chk = lane & 7;
    const int a_scol = ((a_chk ^ a_row) * 8);

    const int lrow = lane & 15;
    const int kc = lane >> 4;
    const int r7 = lrow & 7;

    f32x4 acc[MI][NI] = {};

    for (int k0 = 0; k0 < K; k0 += 64){
#pragma unroll
        for (int j = 0; j < SAW; ++j){
            int seg = wave * SAW + j;
            const __hip_bfloat16* src = A + (size_t)(brow + seg * 8 + a_row) * lda + k0 + a_scol;
            gl_lds16(src, &As[seg * 512]);
        }
#pragma unroll
        for (int j = 0; j < SBW; ++j){
            int seg = wave * SBW + j;
            const __hip_bfloat16* src = W + (size_t)(bcol + seg * 8 + a_row) * K + k0 + a_scol;
            gl_lds16(src, &Ws[seg * 512]);
        }
        __syncthreads();
#pragma unroll
        for (int kk = 0; kk < 2; ++kk){
            int kchunk = kk * 4 + kc;
            short8 af[MI], bfr[NI];
#pragma unroll
            for (int mi = 0; mi < MI; ++mi){
                int row = wm * WROWS + mi * 16 + lrow;
                af[mi] = *(const short8*)&As[row * 64 + ((kchunk ^ r7) * 8)];
            }
#pragma unroll
            for (int ni = 0; ni < NI; ++ni){
                int row = wn * WCOLS + ni * 16 + lrow;
                bfr[ni] = *(const short8*)&Ws[row * 64 + ((kchunk ^ r7) * 8)];
            }
#pragma unroll
            for (int mi = 0; mi < MI; ++mi)
#pragma unroll
                for (int ni = 0; ni < NI; ++ni)
                    acc[mi][ni] = __builtin_amdgcn_mfma_f32_16x16x32_bf16(af[mi], bfr[ni], acc[mi][ni], 0, 0, 0);
        }
        __syncthreads();
    }

    if (EPI & 16){
#pragma unroll
        for (int ni = 0; ni < NI; ++ni){
            int nl = wn * WCOLS + ni * 16 + lrow;
#pragma unroll
            for (int mi = 0; mi < MI; ++mi){
                int ml = wm * WROWS + mi * 16 + kc * 4;
#pragma unroll
                for (int r = 0; r < 4; ++r)
                    tileT[nl * 65 + ml + r] = acc[mi][ni][r];
            }
        }
        __syncthreads();
        int b = brow >> 12, l0 = brow & 4095;
        int lr = tid & 63, nr = tid >> 6;
        float* out = (float*)Cv;
#pragma unroll
        for (int rr = 0; rr < 16; ++rr){
            int n = rr * 4 + nr;
            size_t o = (size_t)(b * DM + bcol + n) * LSEQ + l0 + lr;
            out[o] = tileT[n * 65 + lr] + bias[bcol + n] + xres[o];
        }
        return;
    }

    if (EPI & 32){
        // fused 3x depthwise "same" conv on xnb + SiLU + add, bf16 write to Acomb (ldc-strided)
#pragma unroll
        for (int ni = 0; ni < NI; ++ni){
            int n = bcol + wn * WCOLS + ni * 16 + lrow;
            float4 wv0 = *(const float4*)&msw[n * 20];
            float4 wv1 = *(const float4*)&msw[n * 20 + 4];
            float4 wv2 = *(const float4*)&msw[n * 20 + 8];
            float4 wv3 = *(const float4*)&msw[n * 20 + 12];
            float4 wv4 = *(const float4*)&msw[n * 20 + 16];
#pragma unroll
            for (int mi = 0; mi < MI; ++mi){
                int m0 = brow + wm * WROWS + mi * 16 + kc * 4;
                int l  = m0 & (LSEQ - 1);
                int bL = m0 - l;
                float v[10];
#pragma unroll
                for (int k = 0; k < 10; ++k){
                    int ll = l - 3 + k;
                    v[k] = ((unsigned)ll < LSEQ) ? b2f(xnb2[(size_t)(bL + ll) * 512 + n]) : 0.f;
                }
#pragma unroll
                for (int r = 0; r < 4; ++r){
                    float a1 = wv3.w + wv0.x * v[r+2] + wv0.y * v[r+3] + wv0.z * v[r+4];
                    float a2 = wv4.x + wv0.w * v[r+1] + wv1.x * v[r+2] + wv1.y * v[r+3]
                                     + wv1.z * v[r+4] + wv1.w * v[r+5];
                    float a3 = wv4.y + wv2.x * v[r] + wv2.y * v[r+1] + wv2.z * v[r+2]
                                     + wv2.w * v[r+3] + wv3.x * v[r+4] + wv3.y * v[r+5]
                                     + wv3.z * v[r+6];
                    float res = acc[mi][ni][r] + silu_f(a1) + silu_f(a2) + silu_f(a3);
                    ((__hip_bfloat16*)Cv)[(size_t)(m0 + r) * ldc + n] = f2b(res);
                }
            }
        }
        return;
    }

#pragma unroll
    for (int ni = 0; ni < NI; ++ni){
        int n = bcol + wn * WCOLS + ni * 16 + lrow;
        if (n >= N) continue;
        float bv = (EPI & 1) ? bias[n] : 0.f;
#pragma unroll
        for (int mi = 0; mi < MI; ++mi){
            int m0 = brow + wm * WROWS + mi * 16 + kc * 4;
#pragma unroll
            for (int r = 0; r < 4; ++r){
                float v = acc[mi][ni][r] + bv;
                if (EPI & 8) ((__hip_bfloat16*)Cv)[(size_t)(m0 + r) * ldc + n] = f2b(v);
                else         ((float*)Cv)[(size_t)(m0 + r) * ldc + n] = v;
            }
        }
    }
}

// ---------------- fused xproj GEMM (32x64, K=512) + dt GEMM (K=16 via one MFMA) + softplus ----------------
__global__ __launch_bounds__(256) void k_xpdt(const __hip_bfloat16* __restrict__ A,    // xcb [8192][512]
                                              const __hip_bfloat16* __restrict__ Wxp,  // [64][512] (rows 48+ zero)
                                              const __hip_bfloat16* __restrict__ Wdt,  // [512][32] (cols 16+ zero)
                                              const float* __restrict__ bdt,
                                              float* __restrict__ xdbl,                // [8192][48] f32
                                              __hip_bfloat16* __restrict__ delta){     // [8192][512]
    __shared__ __align__(16) __hip_bfloat16 As[32 * 64];
    __shared__ __align__(16) __hip_bfloat16 Ws[64 * 64];
    __shared__ __hip_bfloat16 xdl[32][34];
    const int tid = threadIdx.x, wave = tid >> 6, lane = tid & 63;
    const int brow = blockIdx.x * 32;
    const int wm = wave >> 1, wn = wave & 1;
    const int a_row = lane >> 3, a_chk = lane & 7, a_scol = ((a_chk ^ a_row) * 8);
    const int lrow = lane & 15, kc = lane >> 4, r7 = lrow & 7;

    // zero xdl cols 16..33 (k-padding for the K=32 MFMA; pad cols never read)
    for (int i = tid; i < 32 * 18; i += 256){
        int rr = i / 18, cc = 16 + i % 18;
        xdl[rr][cc] = f2b(0.f);
    }

    f32x4 acc[2] = {};
    for (int k0 = 0; k0 < 512; k0 += 64){
        {
            int seg = wave;  // 4 segs of 8 rows = 32 rows
            gl_lds16(A + (size_t)(brow + seg * 8 + a_row) * 512 + k0 + a_scol, &As[seg * 512]);
        }
#pragma unroll
        for (int j = 0; j < 2; ++j){
            int seg = wave * 2 + j;
            gl_lds16(Wxp + (size_t)(seg * 8 + a_row) * 512 + k0 + a_scol, &Ws[seg * 512]);
        }
        __syncthreads();
#pragma unroll
        for (int kk = 0; kk < 2; ++kk){
            int kchunk = kk * 4 + kc;
            short8 af = *(const short8*)&As[(wm * 16 + lrow) * 64 + ((kchunk ^ r7) * 8)];
#pragma unroll
            for (int ni = 0; ni < 2; ++ni){
                short8 bfr = *(const short8*)&Ws[(wn * 32 + ni * 16 + lrow) * 64 + ((kchunk ^ r7) * 8)];
                acc[ni] = __builtin_amdgcn_mfma_f32_16x16x32_bf16(af, bfr, acc[ni], 0, 0, 0);
            }
        }
        __syncthreads();
    }

    // write xdbl (f32, n<48) and stage first 16 cols to LDS for the dt GEMM
#pragma unroll
    for (int ni = 0; ni < 2; ++ni){
        int n = wn * 32 + ni * 16 + lrow;
        if (n < 48){
#pragma unroll
            for (int r = 0; r < 4; ++r){
                int ml = wm * 16 + kc * 4 + r;
                float fv = acc[ni][r];
                xdbl[(size_t)(brow + ml) * 48 + n] = fv;
                if (n < 16) xdl[ml][n] = f2b(fv);
            }
        }
    }
    __syncthreads();

    // dt: delta[32][512] = softplus(xdl[32][k<16] @ Wdt[512][k]^T + bdt); wave w owns col-tiles 8w..8w+7
#pragma unroll
    for (int ct8 = 0; ct8 < 8; ++ct8){
        int ct = wave * 8 + ct8;
        int n = ct * 16 + lrow;
        short8 bfr = *(const short8*)&Wdt[(size_t)n * 32 + kc * 8];
        float bv = bdt[n];
#pragma unroll
        for (int rt = 0; rt < 2; ++rt){
            short8 af = *(const short8*)&xdl[rt * 16 + lrow][kc * 8];
            f32x4 dacc = {};
            dacc = __builtin_amdgcn_mfma_f32_16x16x32_bf16(af, bfr, dacc, 0, 0, 0);
#pragma unroll
            for (int r = 0; r < 4; ++r){
                int m = brow + rt * 16 + kc * 4 + r;
                delta[(size_t)m * 512 + n] = f2b(softplus_f(dacc[r] + bv));
            }
        }
    }
}

// ---------------- causal depthwise conv k=4 + SiLU (bf16 in/out, 4-wide) ----------------
__global__ __launch_bounds__(256) void k_conv(const __hip_bfloat16* __restrict__ xz,
                                              const float* __restrict__ cw,
                                              const float* __restrict__ cb,
                                              __hip_bfloat16* __restrict__ xc){
    int idx = blockIdx.x * 256 + threadIdx.x;   // B*L*DIN/4
    int d4 = (idx & 127) * 4;
    int bl = idx >> 7;
    int l  = bl & (LSEQ - 1);
    const __hip_bfloat16* base = xz + (size_t)bl * DXZ + d4;
    float4 bias = *(const float4*)(cb + d4);
    float acc[4] = {bias.x, bias.y, bias.z, bias.w};
    float4 w0 = *(const float4*)(cw + (d4 + 0) * 4);
    float4 w1 = *(const float4*)(cw + (d4 + 1) * 4);
    float4 w2 = *(const float4*)(cw + (d4 + 2) * 4);
    float4 w3 = *(const float4*)(cw + (d4 + 3) * 4);
    const float* wj[4] = {(const float*)&w0, (const float*)&w1, (const float*)&w2, (const float*)&w3};
#pragma unroll
    for (int t = 0; t < 4; ++t){
        int ls = l - (3 - t);
        if (ls >= 0){
            bf4 v = *(const bf4*)(base - (size_t)(3 - t) * DXZ);
#pragma unroll
            for (int j = 0; j < 4; ++j) acc[j] += wj[j][t] * b2f(v.v[j]);
        }
    }
    bf4 o;
#pragma unroll
    for (int j = 0; j < 4; ++j) o.v[j] = f2b(silu_f(acc[j]));
    *(bf4*)(xc + (size_t)bl * DIN + d4) = o;
}

// ---------------- scan pass 1: per-chunk carries, n-split x2 ----------------
__global__ __launch_bounds__(512) void k_scan1(const __hip_bfloat16* __restrict__ delta,
                                               const __hip_bfloat16* __restrict__ xc,
                                               const float* __restrict__ xdbl,
                                               const float* __restrict__ A_log,
                                               float* __restrict__ Acar,
                                               float* __restrict__ Bcar){
    int bx = blockIdx.x;
    int dh = bx & 1;
    int c  = (bx >> 1) & (NC - 1);
    int b  = bx >> 8;
    int tid = threadIdx.x;
    int dloc = tid >> 1, nh = tid & 1;
    int d = dh * 256 + dloc;
    int n0 = nh * 8;
    __shared__ float Bs[LC][DS];
    {
        int t = tid >> 4, n = tid & 15;
        Bs[t][n] = xdbl[(size_t)(b * LSEQ + c * LC + t) * GXP + RANK + n];
    }
    __syncthreads();
    float Av[8];
    float a1 = -__expf(A_log[d * 16]);
    bool fast = true;
#pragma unroll
    for (int j = 0; j < 8; ++j){
        Av[j] = -__expf(A_log[d * 16 + n0 + j]);
        fast = fast && (fabsf(Av[j] - (float)(n0 + j + 1) * a1) <= 1e-4f * fabsf(Av[j]) + 1e-7f);
    }
    float ap[8], ac[8];
#pragma unroll
    for (int j = 0; j < 8; ++j){ ap[j] = 1.f; ac[j] = 0.f; }
    const __hip_bfloat16* dp = delta + (size_t)(b * LSEQ + c * LC) * DIN + d;
    const __hip_bfloat16* xp = xc    + (size_t)(b * LSEQ + c * LC) * DIN + d;
    if (fast){
        for (int t = 0; t < LC; ++t){
            float de = b2f(dp[(size_t)t * DIN]);
            float u  = de * b2f(xp[(size_t)t * DIN]);
            float p  = __expf(de * a1);
            float p2 = p * p, p4 = p2 * p2, p8 = p4 * p4;
            float da = nh ? p8 * p : p;
#pragma unroll
            for (int j = 0; j < 8; ++j){
                ap[j] *= da;
                ac[j] = da * ac[j] + u * Bs[t][n0 + j];
                da *= p;
            }
        }
    } else {
        for (int t = 0; t < LC; ++t){
            float de = b2f(dp[(size_t)t * DIN]);
            float u  = de * b2f(xp[(size_t)t * DIN]);
#pragma unroll
            for (int j = 0; j < 8; ++j){
                float da = __expf(de * Av[j]);
                ap[j] *= da;
                ac[j] = da * ac[j] + u * Bs[t][n0 + j];
            }
        }
    }
    size_t o = (size_t)c * CSTRIDE + (size_t)(b * DIN + d) * 16 + n0;
    *(float4*)(Acar + o)     = make_float4(ap[0], ap[1], ap[2], ap[3]);
    *(float4*)(Acar + o + 4) = make_float4(ap[4], ap[5], ap[6], ap[7]);
    *(float4*)(Bcar + o)     = make_float4(ac[0], ac[1], ac[2], ac[3]);
    *(float4*)(Bcar + o + 4) = make_float4(ac[4], ac[5], ac[6], ac[7]);
}

// ---------------- scan pass 2: wave-parallel Kogge-Stone prefix over 128 chunks ----------------
__global__ __launch_bounds__(256) void k_scan2(const float* __restrict__ Acar,
                                               const float* __restrict__ Bcar,
                                               float* __restrict__ hinit){
    __shared__ float a_s[NC][33];
    __shared__ float b_s[NC][33];
    __shared__ float h_s[NC][33];
    const int tid = threadIdx.x;
    const int idx0 = blockIdx.x * 32;
    const int s_ld = tid & 31, cr = tid >> 5;
#pragma unroll
    for (int r = 0; r < 16; ++r){
        int c = r * 8 + cr;
        size_t g = (size_t)c * CSTRIDE + idx0 + s_ld;
        a_s[c][s_ld] = Acar[g];
        b_s[c][s_ld] = Bcar[g];
    }
    __syncthreads();
    const int lane = tid & 63, w = tid >> 6;
#pragma unroll
    for (int i = 0; i < 8; ++i){
        int s = w * 8 + i;
        float a0 = a_s[2 * lane][s],     b0 = b_s[2 * lane][s];
        float a1 = a_s[2 * lane + 1][s], b1 = b_s[2 * lane + 1][s];
        float av = a0 * a1, bv = a1 * b0 + b1;
#pragma unroll
        for (int d2 = 1; d2 < 64; d2 <<= 1){
            float ao = __shfl_up(av, d2);
            float bo = __shfl_up(bv, d2);
            if (lane >= d2){ bv = av * bo + bv; av = ao * av; }
        }
        float ax = __shfl_up(av, 1), bx = __shfl_up(bv, 1);
        if (lane == 0){ ax = 1.f; bx = 0.f; }
        h_s[2 * lane][s]     = bx;
        h_s[2 * lane + 1][s] = a0 * bx + b0;
    }
    __syncthreads();
#pragma unroll
    for (int r = 0; r < 16; ++r){
        int c = r * 8 + cr;
        hinit[(size_t)c * CSTRIDE + idx0 + s_ld] = h_s[c][s_ld];
    }
}

// ---------------- scan pass 3: replay (n-split x2) + fused (y + D*xc)*silu(z), bf16 out ----------------
__global__ __launch_bounds__(512) void k_scan3(const __hip_bfloat16* __restrict__ delta,
                                               const __hip_bfloat16* __restrict__ xc,
                                               const __hip_bfloat16* __restrict__ xz,
                                               const float* __restrict__ xdbl,
                                               const float* __restrict__ A_log,
                                               const float* __restrict__ D_ssm,
                                               const float* __restrict__ hinit,
                                               __hip_bfloat16* __restrict__ y){
    int bx = blockIdx.x;
    int dh = bx & 1;
    int c  = (bx >> 1) & (NC - 1);
    int b  = bx >> 8;
    int tid = threadIdx.x;
    int dloc = tid >> 1, nh = tid & 1;
    int d = dh * 256 + dloc;
    int n0 = nh * 8;
    __shared__ float Bs[LC][DS], Cs[LC][DS];
    {
        int t = tid >> 4, n = tid & 15;
        size_t r = (size_t)(b * LSEQ + c * LC + t) * GXP;
        Bs[t][n] = xdbl[r + RANK + n];
        Cs[t][n] = xdbl[r + RANK + DS + n];
    }
    __syncthreads();
    float Av[8];
    float a1 = -__expf(A_log[d * 16]);
    bool fast = true;
#pragma unroll
    for (int j = 0; j < 8; ++j){
        Av[j] = -__expf(A_log[d * 16 + n0 + j]);
        fast = fast && (fabsf(Av[j] - (float)(n0 + j + 1) * a1) <= 1e-4f * fabsf(Av[j]) + 1e-7f);
    }
    float h[8];
    size_t ho = (size_t)c * CSTRIDE + (size_t)(b * DIN + d) * 16 + n0;
    {
        float4 h0 = *(const float4*)(hinit + ho);
        float4 h1 = *(const float4*)(hinit + ho + 4);
        h[0] = h0.x; h[1] = h0.y; h[2] = h0.z; h[3] = h0.w;
        h[4] = h1.x; h[5] = h1.y; h[6] = h1.z; h[7] = h1.w;
    }
    float Dd = D_ssm[d];
    size_t rb = (size_t)(b * LSEQ + c * LC);
    if (fast){
        for (int t = 0; t < LC; ++t){
            size_t row = rb + t;
            float de  = b2f(delta[row * DIN + d]);
            float xcv = b2f(xc[row * DIN + d]);
            float u = de * xcv;
            float p  = __expf(de * a1);
            float p2 = p * p, p4 = p2 * p2, p8 = p4 * p4;
            float da = nh ? p8 * p : p;
            float yv = 0.f;
#pragma unroll
            for (int j = 0; j < 8; ++j){
                h[j] = da * h[j] + u * Bs[t][n0 + j];
                yv += h[j] * Cs[t][n0 + j];
                da *= p;
            }
            yv += __shfl_xor(yv, 1);
            if (nh == 0){
                float zv = b2f(xz[row * DXZ + DIN + d]);
                y[row * DIN + d] = f2b((yv + Dd * xcv) * silu_f(zv));
            }
        }
    } else {
        for (int t = 0; t < LC; ++t){
            size_t row = rb + t;
            float de  = b2f(delta[row * DIN + d]);
            float xcv = b2f(xc[row * DIN + d]);
            float u = de * xcv;
            float yv = 0.f;
#pragma unroll
            for (int j = 0; j < 8; ++j){
                float da = __expf(de * Av[j]);
                h[j] = da * h[j] + u * Bs[t][n0 + j];
                yv += h[j] * Cs[t][n0 + j];
            }
            yv += __shfl_xor(yv, 1);
            if (nh == 0){
                float zv = b2f(xz[row * DXZ + DIN + d]);
                y[row * DIN + d] = f2b((yv + Dd * xcv) * silu_f(zv));
            }
        }
    }
}

extern "C" void kernel_launch(void* const* d_in, const int* in_sizes, int n_in,
                              void* d_out, int out_size, void* d_ws, size_t ws_size,
                              hipStream_t stream){
    const float* x      = (const float*)d_in[0];
    const float* ln_w   = (const float*)d_in[1];
    const float* ln_b   = (const float*)d_in[2];
    const float* W_in   = (const float*)d_in[3];
    const float* conv_w = (const float*)d_in[4];
    const float* conv_b = (const float*)d_in[5];
    const float* W_xproj= (const float*)d_in[6];
    const float* W_dt   = (const float*)d_in[7];
    const float* b_dt   = (const float*)d_in[8];
    const float* A_log  = (const float*)d_in[9];
    const float* D_ssm  = (const float*)d_in[10];
    const float* W_outp = (const float*)d_in[11];
    const float* c1_w   = (const float*)d_in[12];
    const float* c1_b   = (const float*)d_in[13];
    const float* c2_w   = (const float*)d_in[14];
    const float* c2_b   = (const float*)d_in[15];
    const float* c3_w   = (const float*)d_in[16];
    const float* c3_b   = (const float*)d_in[17];
    const float* W_out  = (const float*)d_in[18];
    const float* b_out  = (const float*)d_in[19];
    const float* W_skip = (const float*)d_in[20];
    const float* b_skip = (const float*)d_in[21];
    float* out = (float*)d_out;

    char* base = (char*)d_ws;
    const size_t MB = 1024 * 1024;
    const size_t KB = 1024;
    __hip_bfloat16* Acomb = (__hip_bfloat16*)(base);            // [8192][512]  8 MB
    __hip_bfloat16* xzb   = (__hip_bfloat16*)(base + 8*MB);     // [8192][1024] 16 MB
    __hip_bfloat16* xcb   = (__hip_bfloat16*)(base + 24*MB);    // [8192][512]  8 MB
    float*          xdbl  = (float*)        (base + 32*MB);     // [8192][48]   1.5 MB
    __hip_bfloat16* deltab= (__hip_bfloat16*)(base + 34*MB);    // [8192][512]  8 MB
    float*          Acar  = (float*)        (base + 42*MB);     // 8 MB
    float*          Bcar  = (float*)        (base + 50*MB);     // 8 MB
    float*          hinit = (float*)        (base + 58*MB);     // 8 MB
    __hip_bfloat16* Winb  = (__hip_bfloat16*)(base + 66*MB);            // 512 KB
    __hip_bfloat16* Wxpb  = (__hip_bfloat16*)(base + 66*MB + 512*KB);   // 64 KB
    __hip_bfloat16* Wopb  = (__hip_bfloat16*)(base + 66*MB + 576*KB);   // 256 KB
    __hip_bfloat16* Wcb   = (__hip_bfloat16*)(base + 66*MB + 832*KB);   // 256 KB
    __hip_bfloat16* Wdtb  = (__hip_bfloat16*)(base + 66*MB + 1088*KB);  // 32 KB
    float*          bc    = (float*)        (base + 66*MB + 1120*KB);   // 4 KB
    float*          msw   = (float*)        (base + 66*MB + 1124*KB);   // 20 KB
    __hip_bfloat16* xnb   = Acomb + 256;                        // stride 512
    __hip_bfloat16* ybf   = (__hip_bfloat16*)Bcar;              // alias: Bcar dead after scan2

    const int M = BSZ * LSEQ;   // 8192

    // 1: ln + all weight cvt/pack
    k_pre<<<dim3(512), dim3(256), 0, stream>>>(x, ln_w, ln_b, W_in, W_xproj, W_outp, W_out, W_skip,
                                               b_out, b_skip, W_dt, c1_w, c1_b, c2_w, c2_b, c3_w, c3_b,
                                               xnb, Winb, Wxpb, Wopb, Wcb, Wdtb, bc, msw);
    // 2: xz = xn @ W_in^T            M=8192 N=1024 K=256  (128x128 tile)
    k_mgemm<8, 128, 128><<<dim3(64, 8), dim3(256), 0, stream>>>(xnb, 512, Winb, nullptr, xzb, DXZ, 1024, 256);
    // 3: causal conv + silu
    k_conv<<<dim3(M * DIN / 4 / 256), dim3(256), 0, stream>>>(xzb, conv_w, conv_b, xcb);
    // 4: xdbl = xc @ W_xproj^T (f32) AND delta = softplus(xdbl[:,:16] @ W_dt^T + b_dt) (bf16) fused
    k_xpdt<<<dim3(256), dim3(256), 0, stream>>>(xcb, Wxpb, Wdtb, b_dt, xdbl, deltab);
    // 5-7: chunked selective scan
    k_scan1<<<dim3(BSZ * NC * 2), dim3(512), 0, stream>>>(deltab, xcb, xdbl, A_log, Acar, Bcar);
    k_scan2<<<dim3(512), dim3(256), 0, stream>>>(Acar, Bcar, hinit);
    k_scan3<<<dim3(BSZ * NC * 2), dim3(512), 0, stream>>>(deltab, xcb, xzb, xdbl, A_log, D_ssm, hinit, ybf);
    // 8: xssm = y @ W_outp^T + fused msconv epilogue -> Acomb cols 0..255 (bf16)
    k_mgemm<32, 64, 64><<<dim3(128, 4), dim3(256), 0, stream>>>(ybf, 512, Wopb, nullptr, Acomb, 512, 256, 512,
                                                                nullptr, xnb, msw);
    // 9: out = transpose([xssm+conv | xn] @ [W_out|W_skip]^T + bc) + x  (fused epilogue)
    k_mgemm<17, 64, 64><<<dim3(128, 4), dim3(256), 0, stream>>>(Acomb, 512, Wcb, bc, out, DM, 256, 512, x);
}